// Round 1
// baseline (2201.634 us; speedup 1.0000x reference)
//
#include <hip/hip_runtime.h>

typedef unsigned short u16;
typedef __attribute__((ext_vector_type(8))) short bh8;   // 8 x bf16 (raw bits)
typedef __attribute__((ext_vector_type(4))) float f4v;   // MFMA C frag

#define NN 8192
#define EE 262144
#define VDIM 256
#define EDIM 256
#define HDIM 512
#define DAMP 0.45f

__device__ __forceinline__ float b2f(u16 u){ unsigned int x = ((unsigned int)u)<<16; return __builtin_bit_cast(float, x); }
__device__ __forceinline__ u16 f2b(float f){ unsigned int x = __builtin_bit_cast(unsigned int, f); x = (x + 0x7fffu + ((x>>16)&1u)) >> 16; return (u16)x; }

// ---------------- CSR build ----------------
__global__ __launch_bounds__(256) void k_hist(const int* __restrict__ src, int* __restrict__ deg){
  int e = blockIdx.x*256 + threadIdx.x;
  if (e < EE) atomicAdd(&deg[src[e]], 1);
}

__global__ __launch_bounds__(1024) void k_scan(const int* __restrict__ deg, int* __restrict__ ofs, int* __restrict__ cur){
  __shared__ int lds[1024];
  int t = threadIdx.x;
  int v[8], pre[8]; int s = 0;
  #pragma unroll
  for (int j=0;j<8;++j){ v[j] = deg[t*8+j]; }
  #pragma unroll
  for (int j=0;j<8;++j){ pre[j] = s; s += v[j]; }
  lds[t] = s; __syncthreads();
  int run = s;
  for (int off=1; off<1024; off<<=1){
    int x = (t>=off) ? lds[t-off] : 0;
    __syncthreads();
    lds[t] += x;
    __syncthreads();
  }
  int excl = lds[t] - run;
  #pragma unroll
  for (int j=0;j<8;++j){ int o = excl + pre[j]; ofs[t*8+j] = o; cur[t*8+j] = o; }
  if (t == 1023) ofs[NN] = excl + run;
}

__global__ __launch_bounds__(256) void k_permute(const int* __restrict__ src, int* __restrict__ cur, int* __restrict__ elist){
  int e = blockIdx.x*256 + threadIdx.x;
  if (e < EE){ int p = atomicAdd(&cur[src[e]], 1); elist[p] = e; }
}

// ---------------- bf16 MFMA GEMM: C = A @ B^T (+ epilogue) ----------------
// A: [M,K] (f32 or bf16 per template), B: [N,K] f32 (converted while staging)
// EPI 0: f32 out + bias ; EPI 1: bf16 out + bias ; EPI 2: f32 out + c_e*rowterm + constterm
template<int A_BF16, int EPI>
__global__ __launch_bounds__(256)
void k_gemm(const void* __restrict__ Aptr, const float* __restrict__ Bptr,
            int M, int N, int K, const float* __restrict__ bias,
            void* __restrict__ Cptr,
            const int* __restrict__ srcIdx, const float* __restrict__ nsArr,
            const float* __restrict__ rowterm, const float* __restrict__ constterm)
{
  __shared__ u16 As[128*32];
  __shared__ u16 Bs[128*32];
  const int t = threadIdx.x;
  const int m0 = blockIdx.y*128, n0 = blockIdx.x*128;
  const int wid = t>>6, lane = t&63, l15 = lane&15, grp = lane>>4;
  const int wm = (wid>>1)*64, wn = (wid&1)*64;
  const int srow = t>>1, shalf = t&1;

  f4v acc[4][4];
  #pragma unroll
  for (int i=0;i<4;++i)
    #pragma unroll
    for (int j=0;j<4;++j) acc[i][j] = (f4v)0.0f;

  for (int kt=0; kt<K; kt+=32){
    __syncthreads();
    { // stage A tile [128][32]
      u16* dst = &As[srow*32 + shalf*16];
      if (A_BF16){
        const u16* ap = (const u16*)Aptr + (size_t)(m0+srow)*K + kt + shalf*16;
        ((bh8*)dst)[0] = ((const bh8*)ap)[0];
        ((bh8*)dst)[1] = ((const bh8*)ap)[1];
      } else {
        const float* ap = (const float*)Aptr + (size_t)(m0+srow)*K + kt + shalf*16;
        const f4v* ap4 = (const f4v*)ap;
        f4v f0 = ap4[0], f1 = ap4[1], f2 = ap4[2], f3 = ap4[3];
        bh8 v0, v1;
        #pragma unroll
        for (int j=0;j<4;++j){ v0[j]=(short)f2b(f0[j]); v0[j+4]=(short)f2b(f1[j]); v1[j]=(short)f2b(f2[j]); v1[j+4]=(short)f2b(f3[j]); }
        ((bh8*)dst)[0] = v0; ((bh8*)dst)[1] = v1;
      }
    }
    { // stage B tile [128][32] (f32 -> bf16)
      u16* dst = &Bs[srow*32 + shalf*16];
      const float* bp = Bptr + (size_t)(n0+srow)*K + kt + shalf*16;
      const f4v* bp4 = (const f4v*)bp;
      f4v f0 = bp4[0], f1 = bp4[1], f2 = bp4[2], f3 = bp4[3];
      bh8 v0, v1;
      #pragma unroll
      for (int j=0;j<4;++j){ v0[j]=(short)f2b(f0[j]); v0[j+4]=(short)f2b(f1[j]); v1[j]=(short)f2b(f2[j]); v1[j+4]=(short)f2b(f3[j]); }
      ((bh8*)dst)[0] = v0; ((bh8*)dst)[1] = v1;
    }
    __syncthreads();
    bh8 af[4], bfv[4];
    #pragma unroll
    for (int f=0; f<4; ++f) af[f]  = *(const bh8*)&As[(wm + f*16 + l15)*32 + grp*8];
    #pragma unroll
    for (int f=0; f<4; ++f) bfv[f] = *(const bh8*)&Bs[(wn + f*16 + l15)*32 + grp*8];
    #pragma unroll
    for (int fi=0; fi<4; ++fi)
      #pragma unroll
      for (int fj=0; fj<4; ++fj)
        acc[fi][fj] = __builtin_amdgcn_mfma_f32_16x16x32_bf16(af[fi], bfv[fj], acc[fi][fj], 0, 0, 0);
  }

  float cvals[4][4];
  if (EPI == 2){
    #pragma unroll
    for (int fi=0; fi<4; ++fi)
      #pragma unroll
      for (int r=0;r<4;++r){
        int e = m0 + wm + fi*16 + grp*4 + r;
        cvals[fi][r] = DAMP * nsArr[srcIdx[e]];
      }
  }
  #pragma unroll
  for (int fj=0; fj<4; ++fj){
    int c = n0 + wn + fj*16 + l15;
    float bv = 0.f, rt = 0.f, ct = 0.f;
    if (EPI == 2){ rt = rowterm[c]; ct = constterm[c]; }
    else if (bias) bv = bias[c];
    #pragma unroll
    for (int fi=0; fi<4; ++fi){
      #pragma unroll
      for (int r=0;r<4;++r){
        size_t rowg = (size_t)(m0 + wm + fi*16 + grp*4 + r);
        float v = acc[fi][fj][r];
        if (EPI == 0)      ((float*)Cptr)[rowg*N + c] = v + bv;
        else if (EPI == 1) ((u16*)Cptr)[rowg*N + c]  = f2b(v + bv);
        else               ((float*)Cptr)[rowg*N + c] = v + cvals[fi][r]*rt + ct;
      }
    }
  }
}

// ---------------- segment sum + node scalar + norms + BN cross terms ----------------
// one block per node; thread t owns columns 2t, 2t+1
__global__ __launch_bounds__(256)
void k_segsum(const ushort2* __restrict__ w2, const float2* __restrict__ o2,
              const int* __restrict__ ofs, const int* __restrict__ elist,
              float* __restrict__ nsA, float* __restrict__ invn, u16* __restrict__ ob,
              float* __restrict__ cross, float* __restrict__ colsum0,
              float* __restrict__ sumc, float* __restrict__ sumc2)
{
  int i = blockIdx.x, t = threadIdx.x;
  int st = ofs[i], en = ofs[i+1];
  float a0 = 0.f, a1 = 0.f;
  for (int j = st; j < en; ++j){
    int e = elist[j];
    ushort2 v = w2[(size_t)e*256 + t];
    a0 += b2f(v.x); a1 += b2f(v.y);
  }
  float2 o = o2[(size_t)i*256 + t];
  float o0 = o.x + DAMP*a0, o1 = o.y + DAMP*a1;

  float nsp = o0 + o1, qp = o0*o0 + o1*o1;
  for (int m = 32; m > 0; m >>= 1){ nsp += __shfl_xor(nsp, m); qp += __shfl_xor(qp, m); }
  __shared__ float r1[4], r2[4];
  int wid = t>>6, lane = t&63;
  if (lane == 0){ r1[wid] = nsp; r2[wid] = qp; }
  __syncthreads();
  float nsv = r1[0]+r1[1]+r1[2]+r1[3];
  float q   = r2[0]+r2[1]+r2[2]+r2[3];
  if (t == 0){
    nsA[i] = nsv;
    invn[i] = rsqrtf(q);
    float degf = (float)(en - st);
    atomicAdd(sumc,  DAMP*degf*nsv);
    atomicAdd(sumc2, DAMP*DAMP*degf*nsv*nsv);
  }
  ushort2 u; u.x = f2b(o0); u.y = f2b(o1);
  ((ushort2*)ob)[(size_t)i*256 + t] = u;
  atomicAdd(&cross[2*t],   DAMP*nsv*a0);
  atomicAdd(&cross[2*t+1], DAMP*nsv*a1);
  atomicAdd(&colsum0[2*t],   a0);
  atomicAdd(&colsum0[2*t+1], a1);
}

// column sum of squares of w (bf16)
__global__ __launch_bounds__(256)
void k_stats(const ushort2* __restrict__ w2, float* __restrict__ colsumsq){
  int t = threadIdx.x;
  float s0 = 0.f, s1 = 0.f;
  for (int r = blockIdx.x; r < EE; r += gridDim.x){
    ushort2 v = w2[(size_t)r*256 + t];
    float f0 = b2f(v.x), f1 = b2f(v.y);
    s0 += f0*f0; s1 += f1*f1;
  }
  atomicAdd(&colsumsq[2*t],   s0);
  atomicAdd(&colsumsq[2*t+1], s1);
}

// out_bf16 [8192][512] -> outT [512][8192]
__global__ __launch_bounds__(256)
void k_transpose(const u16* __restrict__ in, u16* __restrict__ out){
  __shared__ u16 tile[64][65];
  int r0 = blockIdx.x*64, c0 = blockIdx.y*64;
  int t = threadIdx.x;
  int rr = t>>2, cc = (t&3)*16;
  const u16* ip = in + (size_t)(r0+rr)*512 + c0 + cc;
  #pragma unroll
  for (int j=0;j<16;++j) tile[rr][cc+j] = ip[j];
  __syncthreads();
  int cr = t>>2, rb = (t&3)*16;
  u16* op = out + (size_t)(c0+cr)*8192 + r0 + rb;
  #pragma unroll
  for (int j=0;j<16;++j) op[j] = tile[rb+j][cr];
}

__global__ __launch_bounds__(512)
void k_bnfinal(const float* __restrict__ colsum0, const float* __restrict__ colsumsq,
               const float* __restrict__ cross, const float* __restrict__ sumc,
               const float* __restrict__ sumc2, const float* __restrict__ gamma,
               const float* __restrict__ beta, float* __restrict__ alphaA, float* __restrict__ bbA)
{
  int j = threadIdx.x;
  const float invE = 1.0f / (float)EE;
  float mean = (colsum0[j] + sumc[0]) * invE;
  float ex2  = (colsumsq[j] + 2.f*cross[j] + sumc2[0]) * invE;
  float var  = ex2 - mean*mean;
  float is   = rsqrtf(var + 1e-5f);
  float a    = gamma[j]*is;
  alphaA[j]  = a;
  bbA[j]     = beta[j] - mean*a;
}

__global__ __launch_bounds__(512)
void k_wprime(const float* __restrict__ Ww1, const float* __restrict__ alphaA,
              const float* __restrict__ bbA, const float* __restrict__ bw1,
              float* __restrict__ Ww1p, float* __restrict__ rowterm, float* __restrict__ constt)
{
  __shared__ float red[512];
  int k = blockIdx.x, j = threadIdx.x;
  float wv = Ww1[(size_t)k*512 + j];
  float a  = alphaA[j];
  Ww1p[(size_t)k*512 + j] = wv*a;
  red[j] = wv*a; __syncthreads();
  for (int off=256; off>0; off>>=1){ if (j<off) red[j] += red[j+off]; __syncthreads(); }
  if (j == 0) rowterm[k] = red[0];
  __syncthreads();
  red[j] = wv*bbA[j]; __syncthreads();
  for (int off=256; off>0; off>>=1){ if (j<off) red[j] += red[j+off]; __syncthreads(); }
  if (j == 0) constt[k] = red[0] + bw1[k];
}

// ---------------- flash-style cosine-softmax mix ----------------
// Q=K=V=out (bf16). sim in [-1,1] => exp directly, only row denominator tracked.
__global__ __launch_bounds__(256)
void k_attn(const u16* __restrict__ ob, const u16* __restrict__ obT,
            const float* __restrict__ invn, u16* __restrict__ onew)
{
  __shared__ u16 Klds[32*520];
  __shared__ u16 Vt[512*40];
  __shared__ u16 Plds[32*40];
  __shared__ float l_lds[32];
  int t = threadIdx.x, wid = t>>6, lane = t&63, l15 = lane&15, grp = lane>>4;
  int br = blockIdx.x*32;
  if (t < 32) l_lds[t] = 0.f;

  bh8 aq[16];
  {
    const u16* qp = ob + (size_t)(br + (wid&1)*16 + l15)*512;
    #pragma unroll
    for (int ks=0; ks<16; ++ks) aq[ks] = *(const bh8*)(qp + ks*32 + grp*8);
  }
  float invq[4];
  #pragma unroll
  for (int r=0;r<4;++r) invq[r] = invn[br + (wid&1)*16 + grp*4 + r];

  f4v acc[2][8];
  #pragma unroll
  for (int rf=0;rf<2;++rf)
    #pragma unroll
    for (int cf=0;cf<8;++cf) acc[rf][cf] = (f4v)0.0f;
  __syncthreads();

  for (int kv0 = 0; kv0 < NN; kv0 += 32){
    __syncthreads();
    { // stage K rows [32][512] (padded row 520)
      int r = t>>3, seg = t&7;
      const u16* sp = ob + (size_t)(kv0+r)*512 + seg*64;
      u16* dp = &Klds[r*520 + seg*64];
      #pragma unroll
      for (int j=0;j<8;++j) *(bh8*)(dp + j*8) = *(const bh8*)(sp + j*8);
    }
    #pragma unroll
    for (int h=0; h<2; ++h){ // stage V^T [512][32] (padded row 40)
      int c = t + h*256;
      const u16* sp = obT + (size_t)c*8192 + kv0;
      u16* dp = &Vt[c*40];
      #pragma unroll
      for (int j=0;j<4;++j) *(bh8*)(dp + j*8) = *(const bh8*)(sp + j*8);
    }
    __syncthreads();

    // QK^T: wave computes S rows (wid&1)*16, cols (wid>>1)*16
    f4v sfr = (f4v)0.0f;
    {
      const u16* kp = &Klds[((wid>>1)*16 + l15)*520];
      #pragma unroll
      for (int ks=0; ks<16; ++ks){
        bh8 bq = *(const bh8*)(kp + ks*32 + grp*8);
        sfr = __builtin_amdgcn_mfma_f32_16x16x32_bf16(aq[ks], bq, sfr, 0, 0, 0);
      }
    }
    int colg = kv0 + (wid>>1)*16 + l15;
    float invk = invn[colg];
    float pv[4];
    #pragma unroll
    for (int r=0;r<4;++r){
      int rowg = br + (wid&1)*16 + grp*4 + r;
      float s = sfr[r]*invq[r]*invk;
      if (rowg == colg) s = 0.f;
      pv[r] = __expf(s);
    }
    #pragma unroll
    for (int r=0;r<4;++r){
      float rs = pv[r];
      rs += __shfl_xor(rs,1); rs += __shfl_xor(rs,2); rs += __shfl_xor(rs,4); rs += __shfl_xor(rs,8);
      if (l15 == 0) atomicAdd(&l_lds[(wid&1)*16 + grp*4 + r], rs);
    }
    #pragma unroll
    for (int r=0;r<4;++r)
      Plds[((wid&1)*16 + grp*4 + r)*40 + (wid>>1)*16 + l15] = f2b(pv[r]);
    __syncthreads();

    // PV: wave covers all 32 rows x its 128 output cols
    bh8 pa[2];
    #pragma unroll
    for (int rf=0;rf<2;++rf) pa[rf] = *(const bh8*)&Plds[(rf*16 + l15)*40 + grp*8];
    #pragma unroll
    for (int cf=0; cf<8; ++cf){
      bh8 bv = *(const bh8*)&Vt[(wid*128 + cf*16 + l15)*40 + grp*8];
      #pragma unroll
      for (int rf=0;rf<2;++rf)
        acc[rf][cf] = __builtin_amdgcn_mfma_f32_16x16x32_bf16(pa[rf], bv, acc[rf][cf], 0, 0, 0);
    }
  }
  __syncthreads();
  #pragma unroll
  for (int rf=0;rf<2;++rf){
    #pragma unroll
    for (int r=0;r<4;++r){
      float li = 1.f / l_lds[rf*16 + grp*4 + r];
      size_t ro = (size_t)(br + rf*16 + grp*4 + r)*512;
      #pragma unroll
      for (int cf=0;cf<8;++cf)
        onew[ro + wid*128 + cf*16 + l15] = f2b(acc[rf][cf][r]*li);
    }
  }
}

// ---------------- launch ----------------
extern "C" void kernel_launch(void* const* d_in, const int* in_sizes, int n_in,
                              void* d_out, int out_size, void* d_ws, size_t ws_size,
                              hipStream_t stream)
{
  const float* x    = (const float*)d_in[0];
  const float* ew   = (const float*)d_in[1];
  const int*   ei   = (const int*)  d_in[2];
  const float* W0   = (const float*)d_in[3];
  const float* b0   = (const float*)d_in[4];
  const float* Ww0  = (const float*)d_in[5];
  const float* bw0  = (const float*)d_in[6];
  const float* W1   = (const float*)d_in[7];
  const float* b1   = (const float*)d_in[8];
  const float* Ww1  = (const float*)d_in[9];
  const float* bw1  = (const float*)d_in[10];
  const float* gamma= (const float*)d_in[11];
  const float* beta = (const float*)d_in[12];
  const int* src = ei; // edge_index[0]

  char* ws = (char*)d_ws;
  u16*   w0    = (u16*)  (ws + 0ULL);            // [E][512] bf16  268435456
  float* out0  = (float*)(ws + 268435456ULL);    // [N][512] f32   16777216
  u16*   ob    = (u16*)  (ws + 285212672ULL);    // out bf16       8388608
  u16*   obT   = (u16*)  (ws + 293601280ULL);    // out^T bf16     8388608
  u16*   onew  = (u16*)  (ws + 301989888ULL);    // mixed out bf16 8388608
  float* nsA   = (float*)(ws + 310378496ULL);    // [N]
  float* invn  = (float*)(ws + 310411264ULL);    // [N]
  int*   deg   = (int*)  (ws + 310444032ULL);    // [N]
  int*   ofs   = (int*)  (ws + 310476800ULL);    // [N+1]
  int*   cur   = (int*)  (ws + 310509824ULL);    // [N]
  int*   elist = (int*)  (ws + 310542592ULL);    // [E]
  float* stats = (float*)(ws + 311591168ULL);    // 4096 floats zeroed
  float* cross    = stats;
  float* colsum0  = stats + 512;
  float* colsumsq = stats + 1024;
  float* sumc     = stats + 1536;
  float* sumc2    = stats + 1537;
  float* Ww1p   = (float*)(ws + 311607552ULL);   // [256][512] f32
  float* rowterm= (float*)(ws + 312131840ULL);   // [256]
  float* constt = (float*)(ws + 312132864ULL);   // [256]
  float* alphaA = (float*)(ws + 312133888ULL);   // [512]
  float* bbA    = (float*)(ws + 312135936ULL);   // [512]

  float* out1 = (float*)d_out;                 // [N][256]
  float* out2 = out1 + (size_t)NN*VDIM;        // [E][256]

  hipMemsetAsync(deg, 0, NN*sizeof(int), stream);
  hipMemsetAsync(stats, 0, 16384, stream);

  k_hist   <<<EE/256, 256, 0, stream>>>(src, deg);
  k_scan   <<<1, 1024, 0, stream>>>(deg, ofs, cur);
  k_permute<<<EE/256, 256, 0, stream>>>(src, cur, elist);

  // w = edge_weight @ Ww0^T + bw0  -> bf16
  k_gemm<0,1><<<dim3(4,2048), 256, 0, stream>>>(ew, Ww0, EE, HDIM, EDIM, bw0, w0,
                                                nullptr, nullptr, nullptr, nullptr);
  // out0 = x @ W0^T + b0 -> f32
  k_gemm<0,0><<<dim3(4,64), 256, 0, stream>>>(x, W0, NN, HDIM, VDIM, b0, out0,
                                              nullptr, nullptr, nullptr, nullptr);

  k_segsum<<<NN, 256, 0, stream>>>((const ushort2*)w0, (const float2*)out0, ofs, elist,
                                   nsA, invn, ob, cross, colsum0, sumc, sumc2);
  k_stats<<<1024, 256, 0, stream>>>((const ushort2*)w0, colsumsq);
  k_transpose<<<dim3(128,8), 256, 0, stream>>>(ob, obT);
  k_bnfinal<<<1, 512, 0, stream>>>(colsum0, colsumsq, cross, sumc, sumc2, gamma, beta, alphaA, bbA);
  k_wprime<<<256, 512, 0, stream>>>(Ww1, alphaA, bbA, bw1, Ww1p, rowterm, constt);

  k_attn<<<NN/32, 256, 0, stream>>>(ob, obT, invn, onew);

  // out2 = bn(w') @ Ww1^T + bw1 via affine fold
  k_gemm<1,2><<<dim3(2,2048), 256, 0, stream>>>(w0, Ww1p, EE, EDIM, HDIM, nullptr, out2,
                                                src, nsA, rowterm, constt);
  // out1 = mixed_out @ W1^T + b1
  k_gemm<1,0><<<dim3(2,64), 256, 0, stream>>>(onew, W1, NN, VDIM, HDIM, b1, out1,
                                              nullptr, nullptr, nullptr, nullptr);
}

// Round 2
// 1449.642 us; speedup vs baseline: 1.5187x; 1.5187x over previous
//
#include <hip/hip_runtime.h>

typedef unsigned short u16;
typedef __attribute__((ext_vector_type(8))) short bh8;   // 8 x bf16 (raw bits)
typedef __attribute__((ext_vector_type(4))) float f4v;   // MFMA C frag

#define NN 8192
#define EE 262144
#define VDIM 256
#define EDIM 256
#define HDIM 512
#define DAMP 0.45f

__device__ __forceinline__ float b2f(u16 u){ unsigned int x = ((unsigned int)u)<<16; return __builtin_bit_cast(float, x); }
__device__ __forceinline__ u16 f2b(float f){ unsigned int x = __builtin_bit_cast(unsigned int, f); x = (x + 0x7fffu + ((x>>16)&1u)) >> 16; return (u16)x; }

__device__ __forceinline__ void gload16(const void* g, void* l){
  __builtin_amdgcn_global_load_lds((const __attribute__((address_space(1))) void*)g,
                                   (__attribute__((address_space(3))) void*)l, 16, 0, 0);
}

// ---------------- CSR build ----------------
__global__ __launch_bounds__(256) void k_hist(const int* __restrict__ src, int* __restrict__ deg){
  int e = blockIdx.x*256 + threadIdx.x;
  if (e < EE) atomicAdd(&deg[src[e]], 1);
}

__global__ __launch_bounds__(1024) void k_scan(const int* __restrict__ deg, int* __restrict__ ofs, int* __restrict__ cur){
  __shared__ int lds[1024];
  int t = threadIdx.x;
  int v[8], pre[8]; int s = 0;
  #pragma unroll
  for (int j=0;j<8;++j){ v[j] = deg[t*8+j]; }
  #pragma unroll
  for (int j=0;j<8;++j){ pre[j] = s; s += v[j]; }
  lds[t] = s; __syncthreads();
  int run = s;
  for (int off=1; off<1024; off<<=1){
    int x = (t>=off) ? lds[t-off] : 0;
    __syncthreads();
    lds[t] += x;
    __syncthreads();
  }
  int excl = lds[t] - run;
  #pragma unroll
  for (int j=0;j<8;++j){ int o = excl + pre[j]; ofs[t*8+j] = o; cur[t*8+j] = o; }
  if (t == 1023) ofs[NN] = excl + run;
}

__global__ __launch_bounds__(256) void k_permute(const int* __restrict__ src, int* __restrict__ cur, int* __restrict__ elist){
  int e = blockIdx.x*256 + threadIdx.x;
  if (e < EE){ int p = atomicAdd(&cur[src[e]], 1); elist[p] = e; }
}

// ---------------- bf16 MFMA GEMM: C = A @ B^T (+ epilogue) ----------------
// A: [M,K], B: [N,K]. Per-operand: bf16 (global_load_lds) or f32 (convert while staging).
// EPI 0: f32 out + bias
// EPI 1: bf16 out + bias
// EPI 2: f32 out + c_e*rowterm + constterm   (BN-folded edge output)
// EPI 3: P = exp(scale) bf16 out + row-sum atomics (attention pass 1)
// EPI 4: bf16 out, scaled by 1/lsum[row]          (attention pass 2)
template<int A_BF16, int B_BF16, int EPI>
__global__ __launch_bounds__(256)
void k_gemm(const void* __restrict__ Aptr, const void* __restrict__ Bptr,
            int M, int N, int K, const float* __restrict__ bias,
            void* __restrict__ Cptr,
            const int* __restrict__ srcIdx, const float* __restrict__ nsArr,
            const float* __restrict__ rowterm, const float* __restrict__ constterm,
            const float* __restrict__ invnA, float* __restrict__ lsum)
{
  __shared__ u16 As[128*32];
  __shared__ u16 Bs[128*32];
  const int t = threadIdx.x;
  const int m0 = blockIdx.y*128, n0 = blockIdx.x*128;
  const int wid = t>>6, lane = t&63, l15 = lane&15, grp = lane>>4;
  const int wm = (wid>>1)*64, wn = (wid&1)*64;
  const int srow = t>>1, shalf = t&1;
  const int rlane = lane>>2, clane = lane&3;

  f4v acc[4][4];
  #pragma unroll
  for (int i=0;i<4;++i)
    #pragma unroll
    for (int j=0;j<4;++j) acc[i][j] = (f4v)0.0f;

  for (int kt=0; kt<K; kt+=32){
    __syncthreads();
    if (A_BF16){ // async direct global->LDS, 16B/lane
      const u16* g0 = (const u16*)Aptr + (size_t)(m0 + wid*32 + rlane)*K + kt + clane*8;
      gload16(g0,                 &As[wid*1024]);
      gload16(g0 + (size_t)16*K,  &As[wid*1024 + 512]);
    } else { // stage A tile [128][32] f32 -> bf16
      u16* dst = &As[srow*32 + shalf*16];
      const float* ap = (const float*)Aptr + (size_t)(m0+srow)*K + kt + shalf*16;
      const f4v* ap4 = (const f4v*)ap;
      f4v f0 = ap4[0], f1 = ap4[1], f2 = ap4[2], f3 = ap4[3];
      bh8 v0, v1;
      #pragma unroll
      for (int j=0;j<4;++j){ v0[j]=(short)f2b(f0[j]); v0[j+4]=(short)f2b(f1[j]); v1[j]=(short)f2b(f2[j]); v1[j+4]=(short)f2b(f3[j]); }
      ((bh8*)dst)[0] = v0; ((bh8*)dst)[1] = v1;
    }
    if (B_BF16){
      const u16* g0 = (const u16*)Bptr + (size_t)(n0 + wid*32 + rlane)*K + kt + clane*8;
      gload16(g0,                 &Bs[wid*1024]);
      gload16(g0 + (size_t)16*K,  &Bs[wid*1024 + 512]);
    } else { // stage B tile [128][32] f32 -> bf16
      u16* dst = &Bs[srow*32 + shalf*16];
      const float* bp = (const float*)Bptr + (size_t)(n0+srow)*K + kt + shalf*16;
      const f4v* bp4 = (const f4v*)bp;
      f4v f0 = bp4[0], f1 = bp4[1], f2 = bp4[2], f3 = bp4[3];
      bh8 v0, v1;
      #pragma unroll
      for (int j=0;j<4;++j){ v0[j]=(short)f2b(f0[j]); v0[j+4]=(short)f2b(f1[j]); v1[j]=(short)f2b(f2[j]); v1[j+4]=(short)f2b(f3[j]); }
      ((bh8*)dst)[0] = v0; ((bh8*)dst)[1] = v1;
    }
    __syncthreads();
    bh8 af[4], bfv[4];
    #pragma unroll
    for (int f=0; f<4; ++f) af[f]  = *(const bh8*)&As[(wm + f*16 + l15)*32 + grp*8];
    #pragma unroll
    for (int f=0; f<4; ++f) bfv[f] = *(const bh8*)&Bs[(wn + f*16 + l15)*32 + grp*8];
    #pragma unroll
    for (int fi=0; fi<4; ++fi)
      #pragma unroll
      for (int fj=0; fj<4; ++fj)
        acc[fi][fj] = __builtin_amdgcn_mfma_f32_16x16x32_bf16(af[fi], bfv[fj], acc[fi][fj], 0, 0, 0);
  }

  if (EPI == 3){ // attention pass 1: P = exp(acc*invn_r*invn_c), diag=1; rowsum atomics
    float ic[4];
    #pragma unroll
    for (int fj=0; fj<4; ++fj) ic[fj] = invnA[n0 + wn + fj*16 + l15];
    #pragma unroll
    for (int fi=0; fi<4; ++fi){
      #pragma unroll
      for (int r=0;r<4;++r){
        int rowg = m0 + wm + fi*16 + grp*4 + r;
        float iq = invnA[rowg];
        float rs = 0.f;
        #pragma unroll
        for (int fj=0; fj<4; ++fj){
          int c = n0 + wn + fj*16 + l15;
          float s = acc[fi][fj][r]*iq*ic[fj];
          float p = (rowg == c) ? 1.0f : __expf(s);
          ((u16*)Cptr)[(size_t)rowg*N + c] = f2b(p);
          rs += p;
        }
        rs += __shfl_xor(rs,1); rs += __shfl_xor(rs,2); rs += __shfl_xor(rs,4); rs += __shfl_xor(rs,8);
        if (l15 == 0) atomicAdd(&lsum[rowg], rs);
      }
    }
    return;
  }

  float cvals[4][4];
  if (EPI == 2){
    #pragma unroll
    for (int fi=0; fi<4; ++fi)
      #pragma unroll
      for (int r=0;r<4;++r){
        int e = m0 + wm + fi*16 + grp*4 + r;
        cvals[fi][r] = DAMP * nsArr[srcIdx[e]];
      }
  }
  float ilv[4][4];
  if (EPI == 4){
    #pragma unroll
    for (int fi=0; fi<4; ++fi)
      #pragma unroll
      for (int r=0;r<4;++r)
        ilv[fi][r] = 1.0f / lsum[m0 + wm + fi*16 + grp*4 + r];
  }
  #pragma unroll
  for (int fj=0; fj<4; ++fj){
    int c = n0 + wn + fj*16 + l15;
    float bv = 0.f, rt = 0.f, ct = 0.f;
    if (EPI == 2){ rt = rowterm[c]; ct = constterm[c]; }
    else if (EPI != 4 && bias) bv = bias[c];
    #pragma unroll
    for (int fi=0; fi<4; ++fi){
      #pragma unroll
      for (int r=0;r<4;++r){
        size_t rowg = (size_t)(m0 + wm + fi*16 + grp*4 + r);
        float v = acc[fi][fj][r];
        if (EPI == 0)      ((float*)Cptr)[rowg*N + c] = v + bv;
        else if (EPI == 1) ((u16*)Cptr)[rowg*N + c]  = f2b(v + bv);
        else if (EPI == 2) ((float*)Cptr)[rowg*N + c] = v + cvals[fi][r]*rt + ct;
        else               ((u16*)Cptr)[rowg*N + c]  = f2b(v * ilv[fi][r]);
      }
    }
  }
}

// ---------------- segment sum + node scalar + norms + BN cross terms ----------------
__global__ __launch_bounds__(256)
void k_segsum(const ushort2* __restrict__ w2, const float2* __restrict__ o2,
              const int* __restrict__ ofs, const int* __restrict__ elist,
              float* __restrict__ nsA, float* __restrict__ invn, u16* __restrict__ ob,
              float* __restrict__ cross, float* __restrict__ colsum0,
              float* __restrict__ sumc, float* __restrict__ sumc2)
{
  int i = blockIdx.x, t = threadIdx.x;
  int st = ofs[i], en = ofs[i+1];
  float a0 = 0.f, a1 = 0.f;
  for (int j = st; j < en; ++j){
    int e = elist[j];
    ushort2 v = w2[(size_t)e*256 + t];
    a0 += b2f(v.x); a1 += b2f(v.y);
  }
  float2 o = o2[(size_t)i*256 + t];
  float o0 = o.x + DAMP*a0, o1 = o.y + DAMP*a1;

  float nsp = o0 + o1, qp = o0*o0 + o1*o1;
  for (int m = 32; m > 0; m >>= 1){ nsp += __shfl_xor(nsp, m); qp += __shfl_xor(qp, m); }
  __shared__ float r1[4], r2[4];
  int wid = t>>6, lane = t&63;
  if (lane == 0){ r1[wid] = nsp; r2[wid] = qp; }
  __syncthreads();
  float nsv = r1[0]+r1[1]+r1[2]+r1[3];
  float q   = r2[0]+r2[1]+r2[2]+r2[3];
  if (t == 0){
    nsA[i] = nsv;
    invn[i] = rsqrtf(q);
    float degf = (float)(en - st);
    atomicAdd(sumc,  DAMP*degf*nsv);
    atomicAdd(sumc2, DAMP*DAMP*degf*nsv*nsv);
  }
  ushort2 u; u.x = f2b(o0); u.y = f2b(o1);
  ((ushort2*)ob)[(size_t)i*256 + t] = u;
  atomicAdd(&cross[2*t],   DAMP*nsv*a0);
  atomicAdd(&cross[2*t+1], DAMP*nsv*a1);
  atomicAdd(&colsum0[2*t],   a0);
  atomicAdd(&colsum0[2*t+1], a1);
}

// column sum of squares of w (bf16)
__global__ __launch_bounds__(256)
void k_stats(const ushort2* __restrict__ w2, float* __restrict__ colsumsq){
  int t = threadIdx.x;
  float s0 = 0.f, s1 = 0.f;
  for (int r = blockIdx.x; r < EE; r += gridDim.x){
    ushort2 v = w2[(size_t)r*256 + t];
    float f0 = b2f(v.x), f1 = b2f(v.y);
    s0 += f0*f0; s1 += f1*f1;
  }
  atomicAdd(&colsumsq[2*t],   s0);
  atomicAdd(&colsumsq[2*t+1], s1);
}

// out_bf16 [8192][512] -> outT [512][8192]
__global__ __launch_bounds__(256)
void k_transpose(const u16* __restrict__ in, u16* __restrict__ out){
  __shared__ u16 tile[64][65];
  int r0 = blockIdx.x*64, c0 = blockIdx.y*64;
  int t = threadIdx.x;
  int rr = t>>2, cc = (t&3)*16;
  const u16* ip = in + (size_t)(r0+rr)*512 + c0 + cc;
  #pragma unroll
  for (int j=0;j<16;++j) tile[rr][cc+j] = ip[j];
  __syncthreads();
  int cr = t>>2, rb = (t&3)*16;
  u16* op = out + (size_t)(c0+cr)*8192 + r0 + rb;
  #pragma unroll
  for (int j=0;j<16;++j) op[j] = tile[rb+j][cr];
}

__global__ __launch_bounds__(512)
void k_bnfinal(const float* __restrict__ colsum0, const float* __restrict__ colsumsq,
               const float* __restrict__ cross, const float* __restrict__ sumc,
               const float* __restrict__ sumc2, const float* __restrict__ gamma,
               const float* __restrict__ beta, float* __restrict__ alphaA, float* __restrict__ bbA)
{
  int j = threadIdx.x;
  const float invE = 1.0f / (float)EE;
  float mean = (colsum0[j] + sumc[0]) * invE;
  float ex2  = (colsumsq[j] + 2.f*cross[j] + sumc2[0]) * invE;
  float var  = ex2 - mean*mean;
  float is   = rsqrtf(var + 1e-5f);
  float a    = gamma[j]*is;
  alphaA[j]  = a;
  bbA[j]     = beta[j] - mean*a;
}

__global__ __launch_bounds__(512)
void k_wprime(const float* __restrict__ Ww1, const float* __restrict__ alphaA,
              const float* __restrict__ bbA, const float* __restrict__ bw1,
              float* __restrict__ Ww1p, float* __restrict__ rowterm, float* __restrict__ constt)
{
  __shared__ float red[512];
  int k = blockIdx.x, j = threadIdx.x;
  float wv = Ww1[(size_t)k*512 + j];
  float a  = alphaA[j];
  Ww1p[(size_t)k*512 + j] = wv*a;
  red[j] = wv*a; __syncthreads();
  for (int off=256; off>0; off>>=1){ if (j<off) red[j] += red[j+off]; __syncthreads(); }
  if (j == 0) rowterm[k] = red[0];
  __syncthreads();
  red[j] = wv*bbA[j]; __syncthreads();
  for (int off=256; off>0; off>>=1){ if (j<off) red[j] += red[j+off]; __syncthreads(); }
  if (j == 0) constt[k] = red[0] + bw1[k];
}

// ---------------- launch ----------------
extern "C" void kernel_launch(void* const* d_in, const int* in_sizes, int n_in,
                              void* d_out, int out_size, void* d_ws, size_t ws_size,
                              hipStream_t stream)
{
  const float* x    = (const float*)d_in[0];
  const float* ew   = (const float*)d_in[1];
  const int*   ei   = (const int*)  d_in[2];
  const float* W0   = (const float*)d_in[3];
  const float* b0   = (const float*)d_in[4];
  const float* Ww0  = (const float*)d_in[5];
  const float* bw0  = (const float*)d_in[6];
  const float* W1   = (const float*)d_in[7];
  const float* b1   = (const float*)d_in[8];
  const float* Ww1  = (const float*)d_in[9];
  const float* bw1  = (const float*)d_in[10];
  const float* gamma= (const float*)d_in[11];
  const float* beta = (const float*)d_in[12];
  const int* src = ei; // edge_index[0]

  char* ws = (char*)d_ws;
  u16*   w0    = (u16*)  (ws + 0ULL);            // [E][512] bf16  268435456
  float* out0  = (float*)(ws + 268435456ULL);    // [N][512] f32   16777216
  u16*   ob    = (u16*)  (ws + 285212672ULL);    // out bf16       8388608
  u16*   obT   = (u16*)  (ws + 293601280ULL);    // out^T bf16     8388608
  u16*   onew  = (u16*)  (ws + 301989888ULL);    // mixed out bf16 8388608
  float* nsA   = (float*)(ws + 310378496ULL);    // [N]
  float* invn  = (float*)(ws + 310411264ULL);    // [N]
  int*   deg   = (int*)  (ws + 310444032ULL);    // [N]
  int*   ofs   = (int*)  (ws + 310476800ULL);    // [N+1]
  int*   cur   = (int*)  (ws + 310509824ULL);    // [N]
  int*   elist = (int*)  (ws + 310542592ULL);    // [E]
  float* stats = (float*)(ws + 311591168ULL);    // 4096 floats zeroed
  float* cross    = stats;
  float* colsum0  = stats + 512;
  float* colsumsq = stats + 1024;
  float* sumc     = stats + 1536;
  float* sumc2    = stats + 1537;
  float* lsum  = (float*)(ws + 311607552ULL);    // [N] f32 rowsums (zeroed) 32768
  float* Ww1p   = (float*)(ws + 311640320ULL);   // [256][512] f32
  float* rowterm= (float*)(ws + 312164608ULL);   // [256]
  float* constt = (float*)(ws + 312165632ULL);   // [256]
  float* alphaA = (float*)(ws + 312166656ULL);   // [512]
  float* bbA    = (float*)(ws + 312168704ULL);   // [512]

  float* out1 = (float*)d_out;                 // [N][256]
  float* out2 = out1 + (size_t)NN*VDIM;        // [E][256]
  u16*   Pbuf = (u16*)out2;                    // P [8192][8192] bf16 scratch inside out2 (dead until final GEMM)

  hipMemsetAsync(deg, 0, NN*sizeof(int), stream);
  hipMemsetAsync(stats, 0, 16384, stream);
  hipMemsetAsync(lsum, 0, NN*sizeof(float), stream);

  k_hist   <<<EE/256, 256, 0, stream>>>(src, deg);
  k_scan   <<<1, 1024, 0, stream>>>(deg, ofs, cur);
  k_permute<<<EE/256, 256, 0, stream>>>(src, cur, elist);

  // w = edge_weight @ Ww0^T + bw0  -> bf16
  k_gemm<0,0,1><<<dim3(4,2048), 256, 0, stream>>>(ew, Ww0, EE, HDIM, EDIM, bw0, w0,
                                                  nullptr, nullptr, nullptr, nullptr, nullptr, nullptr);
  // out0 = x @ W0^T + b0 -> f32
  k_gemm<0,0,0><<<dim3(4,64), 256, 0, stream>>>(x, W0, NN, HDIM, VDIM, b0, out0,
                                                nullptr, nullptr, nullptr, nullptr, nullptr, nullptr);

  k_segsum<<<NN, 256, 0, stream>>>((const ushort2*)w0, (const float2*)out0, ofs, elist,
                                   nsA, invn, ob, cross, colsum0, sumc, sumc2);
  k_stats<<<1024, 256, 0, stream>>>((const ushort2*)w0, colsumsq);
  k_transpose<<<dim3(128,8), 256, 0, stream>>>(ob, obT);
  k_bnfinal<<<1, 512, 0, stream>>>(colsum0, colsumsq, cross, sumc, sumc2, gamma, beta, alphaA, bbA);
  k_wprime<<<256, 512, 0, stream>>>(Ww1, alphaA, bbA, bw1, Ww1p, rowterm, constt);

  // attention pass 1: P = exp(cos-sim - eye), row sums -> lsum
  k_gemm<1,1,3><<<dim3(64,64), 256, 0, stream>>>(ob, ob, NN, NN, HDIM, nullptr, Pbuf,
                                                 nullptr, nullptr, nullptr, nullptr, invn, lsum);
  // attention pass 2: onew = (P @ V) / lsum
  k_gemm<1,1,4><<<dim3(4,64), 256, 0, stream>>>(Pbuf, obT, NN, HDIM, NN, nullptr, onew,
                                                nullptr, nullptr, nullptr, nullptr, nullptr, lsum);

  // out2 = bn(w') @ Ww1^T + bw1 via affine fold  (overwrites Pbuf region)
  k_gemm<1,0,2><<<dim3(2,2048), 256, 0, stream>>>(w0, Ww1p, EE, EDIM, HDIM, nullptr, out2,
                                                  src, nsA, rowterm, constt, nullptr, nullptr);
  // out1 = mixed_out @ W1^T + b1
  k_gemm<1,0,0><<<dim3(2,64), 256, 0, stream>>>(onew, W1, NN, VDIM, HDIM, b1, out1,
                                                nullptr, nullptr, nullptr, nullptr, nullptr, nullptr);
}

// Round 3
// 1189.427 us; speedup vs baseline: 1.8510x; 1.2188x over previous
//
#include <hip/hip_runtime.h>

typedef unsigned short u16;
typedef __attribute__((ext_vector_type(8))) short bh8;   // 8 x bf16 (raw bits)
typedef __attribute__((ext_vector_type(4))) float f4v;   // MFMA C frag

#define NN 8192
#define EE 262144
#define VDIM 256
#define EDIM 256
#define HDIM 512
#define DAMP 0.45f

__device__ __forceinline__ float b2f(u16 u){ unsigned int x = ((unsigned int)u)<<16; return __builtin_bit_cast(float, x); }
__device__ __forceinline__ u16 f2b(float f){ unsigned int x = __builtin_bit_cast(unsigned int, f); x = (x + 0x7fffu + ((x>>16)&1u)) >> 16; return (u16)x; }

__device__ __forceinline__ void gload16(const void* g, void* l){
  __builtin_amdgcn_global_load_lds((const __attribute__((address_space(1))) void*)g,
                                   (__attribute__((address_space(3))) void*)l, 16, 0, 0);
}

// ---------------- CSR build ----------------
__global__ __launch_bounds__(256) void k_hist(const int* __restrict__ src, int* __restrict__ deg){
  int e = blockIdx.x*256 + threadIdx.x;
  if (e < EE) atomicAdd(&deg[src[e]], 1);
}

__global__ __launch_bounds__(1024) void k_scan(const int* __restrict__ deg, int* __restrict__ ofs, int* __restrict__ cur){
  __shared__ int lds[1024];
  int t = threadIdx.x;
  int v[8], pre[8]; int s = 0;
  #pragma unroll
  for (int j=0;j<8;++j){ v[j] = deg[t*8+j]; }
  #pragma unroll
  for (int j=0;j<8;++j){ pre[j] = s; s += v[j]; }
  lds[t] = s; __syncthreads();
  int run = s;
  for (int off=1; off<1024; off<<=1){
    int x = (t>=off) ? lds[t-off] : 0;
    __syncthreads();
    lds[t] += x;
    __syncthreads();
  }
  int excl = lds[t] - run;
  #pragma unroll
  for (int j=0;j<8;++j){ int o = excl + pre[j]; ofs[t*8+j] = o; cur[t*8+j] = o; }
  if (t == 1023) ofs[NN] = excl + run;
}

// writes pos[e] = CSR slot of edge e (inverse permutation)
__global__ __launch_bounds__(256) void k_permute(const int* __restrict__ src, int* __restrict__ cur, int* __restrict__ pos){
  int e = blockIdx.x*256 + threadIdx.x;
  if (e < EE){ int p = atomicAdd(&cur[src[e]], 1); pos[e] = p; }
}

// ---------------- bf16 MFMA GEMM: C = A @ B^T (+ epilogue) ----------------
// A: [M,K], B: [N,K]. Per-operand: bf16 (global_load_lds) or f32 (convert while staging).
// EPI 0: f32 out + bias
// EPI 1: bf16 out + bias
// EPI 2: f32 out + c_e*rowterm + constterm   (BN-folded edge output, A rows natural)
// EPI 3: P = exp(scale) bf16 out + row-sum atomics (attention pass 1)
// EPI 4: bf16 out, scaled by 1/lsum[row]          (attention pass 2)
// EPI 5: bf16 out + bias, rows scatter-written through posArr (CSR sort-on-write)
template<int A_BF16, int B_BF16, int EPI>
__global__ __launch_bounds__(256)
void k_gemm(const void* __restrict__ Aptr, const void* __restrict__ Bptr,
            int M, int N, int K, const float* __restrict__ bias,
            void* __restrict__ Cptr,
            const int* __restrict__ srcIdx, const float* __restrict__ nsArr,
            const float* __restrict__ rowterm, const float* __restrict__ constterm,
            const float* __restrict__ invnA, float* __restrict__ lsum,
            const int* __restrict__ posArr)
{
  __shared__ u16 As[128*32];
  __shared__ u16 Bs[128*32];
  const int t = threadIdx.x;
  const int m0 = blockIdx.y*128, n0 = blockIdx.x*128;
  const int wid = t>>6, lane = t&63, l15 = lane&15, grp = lane>>4;
  const int wm = (wid>>1)*64, wn = (wid&1)*64;
  const int srow = t>>1, shalf = t&1;
  const int rlane = lane>>2, clane = lane&3;

  f4v acc[4][4];
  #pragma unroll
  for (int i=0;i<4;++i)
    #pragma unroll
    for (int j=0;j<4;++j) acc[i][j] = (f4v)0.0f;

  for (int kt=0; kt<K; kt+=32){
    __syncthreads();
    if (A_BF16){ // async direct global->LDS, 16B/lane
      const u16* g0 = (const u16*)Aptr + (size_t)(m0 + wid*32 + rlane)*K + kt + clane*8;
      gload16(g0,                 &As[wid*1024]);
      gload16(g0 + (size_t)16*K,  &As[wid*1024 + 512]);
    } else { // stage A tile [128][32] f32 -> bf16
      u16* dst = &As[srow*32 + shalf*16];
      const float* ap = (const float*)Aptr + (size_t)(m0+srow)*K + kt + shalf*16;
      const f4v* ap4 = (const f4v*)ap;
      f4v f0 = ap4[0], f1 = ap4[1], f2 = ap4[2], f3 = ap4[3];
      bh8 v0, v1;
      #pragma unroll
      for (int j=0;j<4;++j){ v0[j]=(short)f2b(f0[j]); v0[j+4]=(short)f2b(f1[j]); v1[j]=(short)f2b(f2[j]); v1[j+4]=(short)f2b(f3[j]); }
      ((bh8*)dst)[0] = v0; ((bh8*)dst)[1] = v1;
    }
    if (B_BF16){
      const u16* g0 = (const u16*)Bptr + (size_t)(n0 + wid*32 + rlane)*K + kt + clane*8;
      gload16(g0,                 &Bs[wid*1024]);
      gload16(g0 + (size_t)16*K,  &Bs[wid*1024 + 512]);
    } else { // stage B tile [128][32] f32 -> bf16
      u16* dst = &Bs[srow*32 + shalf*16];
      const float* bp = (const float*)Bptr + (size_t)(n0+srow)*K + kt + shalf*16;
      const f4v* bp4 = (const f4v*)bp;
      f4v f0 = bp4[0], f1 = bp4[1], f2 = bp4[2], f3 = bp4[3];
      bh8 v0, v1;
      #pragma unroll
      for (int j=0;j<4;++j){ v0[j]=(short)f2b(f0[j]); v0[j+4]=(short)f2b(f1[j]); v1[j]=(short)f2b(f2[j]); v1[j+4]=(short)f2b(f3[j]); }
      ((bh8*)dst)[0] = v0; ((bh8*)dst)[1] = v1;
    }
    __syncthreads();
    bh8 af[4], bfv[4];
    #pragma unroll
    for (int f=0; f<4; ++f) af[f]  = *(const bh8*)&As[(wm + f*16 + l15)*32 + grp*8];
    #pragma unroll
    for (int f=0; f<4; ++f) bfv[f] = *(const bh8*)&Bs[(wn + f*16 + l15)*32 + grp*8];
    #pragma unroll
    for (int fi=0; fi<4; ++fi)
      #pragma unroll
      for (int fj=0; fj<4; ++fj)
        acc[fi][fj] = __builtin_amdgcn_mfma_f32_16x16x32_bf16(af[fi], bfv[fj], acc[fi][fj], 0, 0, 0);
  }

  if (EPI == 3){ // attention pass 1: P = exp(acc*invn_r*invn_c), diag=1; rowsum atomics
    float ic[4];
    #pragma unroll
    for (int fj=0; fj<4; ++fj) ic[fj] = invnA[n0 + wn + fj*16 + l15];
    #pragma unroll
    for (int fi=0; fi<4; ++fi){
      #pragma unroll
      for (int r=0;r<4;++r){
        int rowg = m0 + wm + fi*16 + grp*4 + r;
        float iq = invnA[rowg];
        float rs = 0.f;
        #pragma unroll
        for (int fj=0; fj<4; ++fj){
          int c = n0 + wn + fj*16 + l15;
          float s = acc[fi][fj][r]*iq*ic[fj];
          float p = (rowg == c) ? 1.0f : __expf(s);
          ((u16*)Cptr)[(size_t)rowg*N + c] = f2b(p);
          rs += p;
        }
        rs += __shfl_xor(rs,1); rs += __shfl_xor(rs,2); rs += __shfl_xor(rs,4); rs += __shfl_xor(rs,8);
        if (l15 == 0) atomicAdd(&lsum[rowg], rs);
      }
    }
    return;
  }

  float cvals[4][4];
  if (EPI == 2){
    #pragma unroll
    for (int fi=0; fi<4; ++fi)
      #pragma unroll
      for (int r=0;r<4;++r){
        int e = m0 + wm + fi*16 + grp*4 + r;
        cvals[fi][r] = DAMP * nsArr[srcIdx[e]];
      }
  }
  float ilv[4][4];
  if (EPI == 4){
    #pragma unroll
    for (int fi=0; fi<4; ++fi)
      #pragma unroll
      for (int r=0;r<4;++r)
        ilv[fi][r] = 1.0f / lsum[m0 + wm + fi*16 + grp*4 + r];
  }
  int prow[4][4];
  #pragma unroll
  for (int fi=0; fi<4; ++fi)
    #pragma unroll
    for (int r=0;r<4;++r){
      int rn = m0 + wm + fi*16 + grp*4 + r;
      prow[fi][r] = (EPI == 5) ? posArr[rn] : rn;
    }
  #pragma unroll
  for (int fj=0; fj<4; ++fj){
    int c = n0 + wn + fj*16 + l15;
    float bv = 0.f, rt = 0.f, ct = 0.f;
    if (EPI == 2){ rt = rowterm[c]; ct = constterm[c]; }
    else if (EPI != 4 && bias) bv = bias[c];
    #pragma unroll
    for (int fi=0; fi<4; ++fi){
      #pragma unroll
      for (int r=0;r<4;++r){
        size_t rowg = (size_t)prow[fi][r];
        float v = acc[fi][fj][r];
        if (EPI == 0)      ((float*)Cptr)[rowg*N + c] = v + bv;
        else if (EPI == 1 || EPI == 5) ((u16*)Cptr)[rowg*N + c] = f2b(v + bv);
        else if (EPI == 2) ((float*)Cptr)[rowg*N + c] = v + cvals[fi][r]*rt + ct;
        else               ((u16*)Cptr)[rowg*N + c]  = f2b(v * ilv[fi][r]);
      }
    }
  }
}

// ---------------- segment sum over CSR-sorted w (contiguous streaming) ----------------
// 4 nodes per block; thread t owns columns 2t, 2t+1. Also accumulates BN stats
// (colsum, colsumsq, cross) in registers, 6 atomics per thread at the end.
__global__ __launch_bounds__(256)
void k_segsum4(const ushort2* __restrict__ w2, const float2* __restrict__ o2,
               const int* __restrict__ ofs,
               float* __restrict__ nsA, float* __restrict__ invn, u16* __restrict__ ob,
               float* __restrict__ cross, float* __restrict__ colsum0, float* __restrict__ colsumsq,
               float* __restrict__ sumc, float* __restrict__ sumc2)
{
  int i0 = blockIdx.x*4, t = threadIdx.x;
  int wid = t>>6, lane = t&63;
  __shared__ float r1[4], r2[4];
  float cs0=0.f, cs1=0.f, sq0=0.f, sq1=0.f, cr0=0.f, cr1=0.f;
  #pragma unroll 1
  for (int u=0; u<4; ++u){
    int i = i0+u;
    int st = ofs[i], en = ofs[i+1];
    float a0=0.f, a1=0.f;
    for (int p=st; p<en; ++p){
      ushort2 v = w2[(size_t)p*256 + t];
      float f0=b2f(v.x), f1=b2f(v.y);
      a0+=f0; a1+=f1; sq0+=f0*f0; sq1+=f1*f1;
    }
    float2 o = o2[(size_t)i*256 + t];
    float o0 = o.x + DAMP*a0, o1 = o.y + DAMP*a1;
    float nsp = o0+o1, qp = o0*o0+o1*o1;
    for (int m=32;m>0;m>>=1){ nsp += __shfl_xor(nsp,m); qp += __shfl_xor(qp,m); }
    if (lane==0){ r1[wid]=nsp; r2[wid]=qp; }
    __syncthreads();
    float nsv = r1[0]+r1[1]+r1[2]+r1[3];
    float q   = r2[0]+r2[1]+r2[2]+r2[3];
    __syncthreads();
    if (t==0){
      nsA[i]=nsv; invn[i]=rsqrtf(q);
      float degf=(float)(en-st);
      atomicAdd(sumc,  DAMP*degf*nsv);
      atomicAdd(sumc2, DAMP*DAMP*degf*nsv*nsv);
    }
    ushort2 uo; uo.x=f2b(o0); uo.y=f2b(o1);
    ((ushort2*)ob)[(size_t)i*256+t]=uo;
    cs0+=a0; cs1+=a1; cr0+=DAMP*nsv*a0; cr1+=DAMP*nsv*a1;
  }
  atomicAdd(&colsum0[2*t],  cs0); atomicAdd(&colsum0[2*t+1],  cs1);
  atomicAdd(&colsumsq[2*t], sq0); atomicAdd(&colsumsq[2*t+1], sq1);
  atomicAdd(&cross[2*t],    cr0); atomicAdd(&cross[2*t+1],    cr1);
}

// out_bf16 [8192][512] -> outT [512][8192]
__global__ __launch_bounds__(256)
void k_transpose(const u16* __restrict__ in, u16* __restrict__ out){
  __shared__ u16 tile[64][65];
  int r0 = blockIdx.x*64, c0 = blockIdx.y*64;
  int t = threadIdx.x;
  int rr = t>>2, cc = (t&3)*16;
  const u16* ip = in + (size_t)(r0+rr)*512 + c0 + cc;
  #pragma unroll
  for (int j=0;j<16;++j) tile[rr][cc+j] = ip[j];
  __syncthreads();
  int cr = t>>2, rb = (t&3)*16;
  u16* op = out + (size_t)(c0+cr)*8192 + r0 + rb;
  #pragma unroll
  for (int j=0;j<16;++j) op[j] = tile[rb+j][cr];
}

__global__ __launch_bounds__(512)
void k_bnfinal(const float* __restrict__ colsum0, const float* __restrict__ colsumsq,
               const float* __restrict__ cross, const float* __restrict__ sumc,
               const float* __restrict__ sumc2, const float* __restrict__ gamma,
               const float* __restrict__ beta, float* __restrict__ alphaA, float* __restrict__ bbA)
{
  int j = threadIdx.x;
  const float invE = 1.0f / (float)EE;
  float mean = (colsum0[j] + sumc[0]) * invE;
  float ex2  = (colsumsq[j] + 2.f*cross[j] + sumc2[0]) * invE;
  float var  = ex2 - mean*mean;
  float is   = rsqrtf(var + 1e-5f);
  float a    = gamma[j]*is;
  alphaA[j]  = a;
  bbA[j]     = beta[j] - mean*a;
}

__global__ __launch_bounds__(512)
void k_wprime(const float* __restrict__ Ww1, const float* __restrict__ alphaA,
              const float* __restrict__ bbA, const float* __restrict__ bw1,
              const float* __restrict__ bw0,
              float* __restrict__ Ww1p, float* __restrict__ rowterm, float* __restrict__ constt)
{
  __shared__ float red[512];
  int k = blockIdx.x, j = threadIdx.x;
  float wv = Ww1[(size_t)k*512 + j];
  float a  = alphaA[j];
  Ww1p[(size_t)k*512 + j] = wv*a;
  red[j] = wv*a; __syncthreads();
  for (int off=256; off>0; off>>=1){ if (j<off) red[j] += red[j+off]; __syncthreads(); }
  if (j == 0) rowterm[k] = red[0];
  __syncthreads();
  red[j] = wv*(bbA[j] + a*bw0[j]); __syncthreads();
  for (int off=256; off>0; off>>=1){ if (j<off) red[j] += red[j+off]; __syncthreads(); }
  if (j == 0) constt[k] = red[0] + bw1[k];
}

// Wc[k][m] = sum_j Ww1p[k][j] * Ww0[j][m]   (256x512 @ 512x256)
__global__ __launch_bounds__(256)
void k_wc(const float* __restrict__ Ww1p, const float* __restrict__ Ww0, float* __restrict__ Wc){
  int k = blockIdx.x, m = threadIdx.x;
  float s = 0.f;
  #pragma unroll 8
  for (int j=0;j<512;++j) s += Ww1p[(size_t)k*512+j] * Ww0[(size_t)j*256+m];
  Wc[(size_t)k*256+m] = s;
}

// ---------------- launch ----------------
extern "C" void kernel_launch(void* const* d_in, const int* in_sizes, int n_in,
                              void* d_out, int out_size, void* d_ws, size_t ws_size,
                              hipStream_t stream)
{
  const float* x    = (const float*)d_in[0];
  const float* ew   = (const float*)d_in[1];
  const int*   ei   = (const int*)  d_in[2];
  const float* W0   = (const float*)d_in[3];
  const float* b0   = (const float*)d_in[4];
  const float* Ww0  = (const float*)d_in[5];
  const float* bw0  = (const float*)d_in[6];
  const float* W1   = (const float*)d_in[7];
  const float* b1   = (const float*)d_in[8];
  const float* Ww1  = (const float*)d_in[9];
  const float* bw1  = (const float*)d_in[10];
  const float* gamma= (const float*)d_in[11];
  const float* beta = (const float*)d_in[12];
  const int* src = ei; // edge_index[0]

  char* ws = (char*)d_ws;
  u16*   w0    = (u16*)  (ws + 0ULL);            // [E][512] bf16, CSR-permuted rows
  float* out0  = (float*)(ws + 268435456ULL);    // [N][512] f32
  u16*   ob    = (u16*)  (ws + 285212672ULL);    // out bf16
  u16*   obT   = (u16*)  (ws + 293601280ULL);    // out^T bf16
  u16*   onew  = (u16*)  (ws + 301989888ULL);    // mixed out bf16 (written late)
  float* nsA   = (float*)(ws + 310378496ULL);    // [N]
  float* invn  = (float*)(ws + 310411264ULL);    // [N]
  int*   deg   = (int*)  (ws + 310444032ULL);    // [N]
  int*   ofs   = (int*)  (ws + 310476800ULL);    // [N+1]
  int*   cur   = (int*)  (ws + 310509824ULL);    // [N]
  float* stats = (float*)(ws + 311591168ULL);    // 4096 floats zeroed
  float* cross    = stats;
  float* colsum0  = stats + 512;
  float* colsumsq = stats + 1024;
  float* sumc     = stats + 1536;
  float* sumc2    = stats + 1537;
  float* lsum  = (float*)(ws + 311607552ULL);    // [N] f32 rowsums (zeroed)
  float* Ww1p   = (float*)(ws + 311640320ULL);   // [256][512] f32
  float* rowterm= (float*)(ws + 312164608ULL);   // [256]
  float* constt = (float*)(ws + 312165632ULL);   // [256]
  float* alphaA = (float*)(ws + 312166656ULL);   // [512]
  float* bbA    = (float*)(ws + 312168704ULL);   // [512]
  // lifetime-overlapped scratch (no new ws space):
  int*   pos   = (int*)onew;      // [E] int; dead before onew is written (attn pass 2)
  float* Wc    = (float*)out0;    // [256][256] f32; out0 dead after k_segsum4

  float* out1 = (float*)d_out;                 // [N][256]
  float* out2 = out1 + (size_t)NN*VDIM;        // [E][256]
  u16*   Pbuf = (u16*)out2;                    // P [8192][8192] bf16 scratch inside out2

  hipMemsetAsync(deg, 0, NN*sizeof(int), stream);
  hipMemsetAsync(stats, 0, 16384, stream);
  hipMemsetAsync(lsum, 0, NN*sizeof(float), stream);

  k_hist   <<<EE/256, 256, 0, stream>>>(src, deg);
  k_scan   <<<1, 1024, 0, stream>>>(deg, ofs, cur);
  k_permute<<<EE/256, 256, 0, stream>>>(src, cur, pos);

  // w = edge_weight @ Ww0^T + bw0 -> bf16, rows scatter-written to CSR order
  k_gemm<0,0,5><<<dim3(4,2048), 256, 0, stream>>>(ew, Ww0, EE, HDIM, EDIM, bw0, w0,
                                                  nullptr, nullptr, nullptr, nullptr, nullptr, nullptr, pos);
  // out0 = x @ W0^T + b0 -> f32
  k_gemm<0,0,0><<<dim3(4,64), 256, 0, stream>>>(x, W0, NN, HDIM, VDIM, b0, out0,
                                                nullptr, nullptr, nullptr, nullptr, nullptr, nullptr, nullptr);

  // segment sums (contiguous CSR ranges) + node scalars + norms + all BN stats
  k_segsum4<<<NN/4, 256, 0, stream>>>((const ushort2*)w0, (const float2*)out0, ofs,
                                      nsA, invn, ob, cross, colsum0, colsumsq, sumc, sumc2);
  k_transpose<<<dim3(128,8), 256, 0, stream>>>(ob, obT);
  k_bnfinal<<<1, 512, 0, stream>>>(colsum0, colsumsq, cross, sumc, sumc2, gamma, beta, alphaA, bbA);
  k_wprime<<<256, 512, 0, stream>>>(Ww1, alphaA, bbA, bw1, bw0, Ww1p, rowterm, constt);
  k_wc<<<256, 256, 0, stream>>>(Ww1p, Ww0, Wc);

  // attention pass 1: P = exp(cos-sim - eye), row sums -> lsum
  k_gemm<1,1,3><<<dim3(64,64), 256, 0, stream>>>(ob, ob, NN, NN, HDIM, nullptr, Pbuf,
                                                 nullptr, nullptr, nullptr, nullptr, invn, lsum, nullptr);
  // attention pass 2: onew = (P @ V) / lsum
  k_gemm<1,1,4><<<dim3(4,64), 256, 0, stream>>>(Pbuf, obT, NN, HDIM, NN, nullptr, onew,
                                                nullptr, nullptr, nullptr, nullptr, nullptr, lsum, nullptr);

  // out2 = ew @ Wc^T + c_e*rowterm + constt   (BN fold pushed through Ww0)
  k_gemm<0,0,2><<<dim3(2,2048), 256, 0, stream>>>(ew, Wc, EE, VDIM, EDIM, nullptr, out2,
                                                  src, nsA, rowterm, constt, nullptr, nullptr, nullptr);
  // out1 = mixed_out @ W1^T + b1
  k_gemm<1,0,0><<<dim3(2,64), 256, 0, stream>>>(onew, W1, NN, VDIM, HDIM, b1, out1,
                                                nullptr, nullptr, nullptr, nullptr, nullptr, nullptr, nullptr);
}

// Round 4
// 1098.675 us; speedup vs baseline: 2.0039x; 1.0826x over previous
//
#include <hip/hip_runtime.h>

typedef unsigned short u16;
typedef __attribute__((ext_vector_type(8))) short bh8;   // 8 x bf16 (raw bits)
typedef __attribute__((ext_vector_type(4))) float f4v;   // MFMA C frag

#define NN 8192
#define EE 262144
#define VDIM 256
#define EDIM 256
#define HDIM 512
#define DAMP 0.45f

__device__ __forceinline__ float b2f(u16 u){ unsigned int x = ((unsigned int)u)<<16; return __builtin_bit_cast(float, x); }
__device__ __forceinline__ u16 f2b(float f){ unsigned int x = __builtin_bit_cast(unsigned int, f); x = (x + 0x7fffu + ((x>>16)&1u)) >> 16; return (u16)x; }

__device__ __forceinline__ void gload16(const void* g, void* l){
  __builtin_amdgcn_global_load_lds((const __attribute__((address_space(1))) void*)g,
                                   (__attribute__((address_space(3))) void*)l, 16, 0, 0);
}

// ---------------- CSR build ----------------
__global__ __launch_bounds__(256) void k_hist(const int* __restrict__ src, int* __restrict__ deg){
  int e = blockIdx.x*256 + threadIdx.x;
  if (e < EE) atomicAdd(&deg[src[e]], 1);
}

__global__ __launch_bounds__(1024) void k_scan(const int* __restrict__ deg, int* __restrict__ ofs, int* __restrict__ cur){
  __shared__ int lds[1024];
  int t = threadIdx.x;
  int v[8], pre[8]; int s = 0;
  #pragma unroll
  for (int j=0;j<8;++j){ v[j] = deg[t*8+j]; }
  #pragma unroll
  for (int j=0;j<8;++j){ pre[j] = s; s += v[j]; }
  lds[t] = s; __syncthreads();
  int run = s;
  for (int off=1; off<1024; off<<=1){
    int x = (t>=off) ? lds[t-off] : 0;
    __syncthreads();
    lds[t] += x;
    __syncthreads();
  }
  int excl = lds[t] - run;
  #pragma unroll
  for (int j=0;j<8;++j){ int o = excl + pre[j]; ofs[t*8+j] = o; cur[t*8+j] = o; }
  if (t == 1023) ofs[NN] = excl + run;
}

// writes pos[e] = CSR slot of edge e (inverse permutation)
__global__ __launch_bounds__(256) void k_permute(const int* __restrict__ src, int* __restrict__ cur, int* __restrict__ pos){
  int e = blockIdx.x*256 + threadIdx.x;
  if (e < EE){ int p = atomicAdd(&cur[src[e]], 1); pos[e] = p; }
}

// ---------------- narrow GEMM (128x128 tile, 256 thr): C = A @ B^T ----------------
// EPI 0: f32 out + bias
// EPI 1: bf16 out + bias
// EPI 3: P = exp(scale) bf16 out + row-sum atomics (attention pass 1)
// EPI 4: bf16 out, scaled by 1/lsum[row]          (attention pass 2)
template<int A_BF16, int B_BF16, int EPI>
__global__ __launch_bounds__(256)
void k_gemm(const void* __restrict__ Aptr, const void* __restrict__ Bptr,
            int M, int N, int K, const float* __restrict__ bias,
            void* __restrict__ Cptr,
            const float* __restrict__ invnA, float* __restrict__ lsum)
{
  __shared__ u16 As[128*32];
  __shared__ u16 Bs[128*32];
  const int t = threadIdx.x;
  const int m0 = blockIdx.y*128, n0 = blockIdx.x*128;
  const int wid = t>>6, lane = t&63, l15 = lane&15, grp = lane>>4;
  const int wm = (wid>>1)*64, wn = (wid&1)*64;
  const int srow = t>>1, shalf = t&1;
  const int rlane = lane>>2, clane = lane&3;

  f4v acc[4][4];
  #pragma unroll
  for (int i=0;i<4;++i)
    #pragma unroll
    for (int j=0;j<4;++j) acc[i][j] = (f4v)0.0f;

  for (int kt=0; kt<K; kt+=32){
    __syncthreads();
    if (A_BF16){ // async direct global->LDS, 16B/lane
      const u16* g0 = (const u16*)Aptr + (size_t)(m0 + wid*32 + rlane)*K + kt + clane*8;
      gload16(g0,                 &As[wid*1024]);
      gload16(g0 + (size_t)16*K,  &As[wid*1024 + 512]);
    } else {
      u16* dst = &As[srow*32 + shalf*16];
      const float* ap = (const float*)Aptr + (size_t)(m0+srow)*K + kt + shalf*16;
      const f4v* ap4 = (const f4v*)ap;
      f4v f0 = ap4[0], f1 = ap4[1], f2 = ap4[2], f3 = ap4[3];
      bh8 v0, v1;
      #pragma unroll
      for (int j=0;j<4;++j){ v0[j]=(short)f2b(f0[j]); v0[j+4]=(short)f2b(f1[j]); v1[j]=(short)f2b(f2[j]); v1[j+4]=(short)f2b(f3[j]); }
      ((bh8*)dst)[0] = v0; ((bh8*)dst)[1] = v1;
    }
    if (B_BF16){
      const u16* g0 = (const u16*)Bptr + (size_t)(n0 + wid*32 + rlane)*K + kt + clane*8;
      gload16(g0,                 &Bs[wid*1024]);
      gload16(g0 + (size_t)16*K,  &Bs[wid*1024 + 512]);
    } else {
      u16* dst = &Bs[srow*32 + shalf*16];
      const float* bp = (const float*)Bptr + (size_t)(n0+srow)*K + kt + shalf*16;
      const f4v* bp4 = (const f4v*)bp;
      f4v f0 = bp4[0], f1 = bp4[1], f2 = bp4[2], f3 = bp4[3];
      bh8 v0, v1;
      #pragma unroll
      for (int j=0;j<4;++j){ v0[j]=(short)f2b(f0[j]); v0[j+4]=(short)f2b(f1[j]); v1[j]=(short)f2b(f2[j]); v1[j+4]=(short)f2b(f3[j]); }
      ((bh8*)dst)[0] = v0; ((bh8*)dst)[1] = v1;
    }
    __syncthreads();
    bh8 af[4], bfv[4];
    #pragma unroll
    for (int f=0; f<4; ++f) af[f]  = *(const bh8*)&As[(wm + f*16 + l15)*32 + grp*8];
    #pragma unroll
    for (int f=0; f<4; ++f) bfv[f] = *(const bh8*)&Bs[(wn + f*16 + l15)*32 + grp*8];
    #pragma unroll
    for (int fi=0; fi<4; ++fi)
      #pragma unroll
      for (int fj=0; fj<4; ++fj)
        acc[fi][fj] = __builtin_amdgcn_mfma_f32_16x16x32_bf16(af[fi], bfv[fj], acc[fi][fj], 0, 0, 0);
  }

  if (EPI == 3){ // attention pass 1
    float ic[4];
    #pragma unroll
    for (int fj=0; fj<4; ++fj) ic[fj] = invnA[n0 + wn + fj*16 + l15];
    #pragma unroll
    for (int fi=0; fi<4; ++fi){
      #pragma unroll
      for (int r=0;r<4;++r){
        int rowg = m0 + wm + fi*16 + grp*4 + r;
        float iq = invnA[rowg];
        float rs = 0.f;
        #pragma unroll
        for (int fj=0; fj<4; ++fj){
          int c = n0 + wn + fj*16 + l15;
          float s = acc[fi][fj][r]*iq*ic[fj];
          float p = (rowg == c) ? 1.0f : __expf(s);
          ((u16*)Cptr)[(size_t)rowg*N + c] = f2b(p);
          rs += p;
        }
        rs += __shfl_xor(rs,1); rs += __shfl_xor(rs,2); rs += __shfl_xor(rs,4); rs += __shfl_xor(rs,8);
        if (l15 == 0) atomicAdd(&lsum[rowg], rs);
      }
    }
    return;
  }

  float ilv[4][4];
  if (EPI == 4){
    #pragma unroll
    for (int fi=0; fi<4; ++fi)
      #pragma unroll
      for (int r=0;r<4;++r)
        ilv[fi][r] = 1.0f / lsum[m0 + wm + fi*16 + grp*4 + r];
  }
  #pragma unroll
  for (int fj=0; fj<4; ++fj){
    int c = n0 + wn + fj*16 + l15;
    float bv = (EPI != 4 && bias) ? bias[c] : 0.f;
    #pragma unroll
    for (int fi=0; fi<4; ++fi){
      #pragma unroll
      for (int r=0;r<4;++r){
        size_t rowg = (size_t)(m0 + wm + fi*16 + grp*4 + r);
        float v = acc[fi][fj][r];
        if (EPI == 0)      ((float*)Cptr)[rowg*N + c] = v + bv;
        else if (EPI == 1) ((u16*)Cptr)[rowg*N + c]  = f2b(v + bv);
        else               ((u16*)Cptr)[rowg*N + c]  = f2b(v * ilv[fi][r]);
      }
    }
  }
}

// ---------------- wide GEMM (128x256 tile, 512 thr, f32 A/B): C = A @ B^T ----------------
// EPI 2: f32 out + c_e*rowterm + constterm (BN-folded edge output)
// EPI 5: bf16 out + bias, rows scatter-written through posArr (CSR sort-on-write)
template<int EPI>
__global__ __launch_bounds__(512)
void k_gemmw(const float* __restrict__ Aptr, const float* __restrict__ Bptr,
             int Nout, int K, const float* __restrict__ bias,
             void* __restrict__ Cptr,
             const int* __restrict__ srcIdx, const float* __restrict__ nsArr,
             const float* __restrict__ rowterm, const float* __restrict__ constterm,
             const int* __restrict__ posArr)
{
  __shared__ u16 As[128*32];
  __shared__ u16 Bs[256*32];
  const int t = threadIdx.x;
  // XCD-chunked bijective swizzle (nwg = gridDim.x*gridDim.y, divisible by 8)
  int linear = blockIdx.y*gridDim.x + blockIdx.x;
  int nwg = gridDim.x*gridDim.y;
  int tile = (linear & 7)*(nwg>>3) + (linear>>3);
  const int m0 = (tile/gridDim.x)*128, n0 = (tile%gridDim.x)*256;
  const int wid = t>>6, lane = t&63, l15 = lane&15, grp = lane>>4;
  const int wm = (wid>>2)*64, wn = (wid&3)*64;

  f4v acc[4][4];
  #pragma unroll
  for (int i=0;i<4;++i)
    #pragma unroll
    for (int j=0;j<4;++j) acc[i][j] = (f4v)0.0f;

  const int arow = t>>2, aseg = t&3;     // A: 128 rows x 4 segs of 8
  const int brow = t>>1, bhalf = t&1;    // B: 256 rows x 2 halves of 16

  for (int kt=0; kt<K; kt+=32){
    __syncthreads();
    { // stage A [128][32] f32->bf16
      const float* ap = Aptr + (size_t)(m0+arow)*K + kt + aseg*8;
      const f4v* ap4 = (const f4v*)ap;
      f4v f0 = ap4[0], f1 = ap4[1];
      bh8 v;
      #pragma unroll
      for (int j=0;j<4;++j){ v[j]=(short)f2b(f0[j]); v[j+4]=(short)f2b(f1[j]); }
      *(bh8*)&As[arow*32 + aseg*8] = v;
    }
    { // stage B [256][32] f32->bf16
      const float* bp = Bptr + (size_t)(n0+brow)*K + kt + bhalf*16;
      const f4v* bp4 = (const f4v*)bp;
      f4v f0 = bp4[0], f1 = bp4[1], f2 = bp4[2], f3 = bp4[3];
      bh8 v0, v1;
      #pragma unroll
      for (int j=0;j<4;++j){ v0[j]=(short)f2b(f0[j]); v0[j+4]=(short)f2b(f1[j]); v1[j]=(short)f2b(f2[j]); v1[j+4]=(short)f2b(f3[j]); }
      u16* dst = &Bs[brow*32 + bhalf*16];
      ((bh8*)dst)[0] = v0; ((bh8*)dst)[1] = v1;
    }
    __syncthreads();
    bh8 af[4], bfv[4];
    #pragma unroll
    for (int f=0; f<4; ++f) af[f]  = *(const bh8*)&As[(wm + f*16 + l15)*32 + grp*8];
    #pragma unroll
    for (int f=0; f<4; ++f) bfv[f] = *(const bh8*)&Bs[(wn + f*16 + l15)*32 + grp*8];
    #pragma unroll
    for (int fi=0; fi<4; ++fi)
      #pragma unroll
      for (int fj=0; fj<4; ++fj)
        acc[fi][fj] = __builtin_amdgcn_mfma_f32_16x16x32_bf16(af[fi], bfv[fj], acc[fi][fj], 0, 0, 0);
  }

  if (EPI == 2){
    float cvals[4][4];
    #pragma unroll
    for (int fi=0; fi<4; ++fi)
      #pragma unroll
      for (int r=0;r<4;++r){
        int e = m0 + wm + fi*16 + grp*4 + r;
        cvals[fi][r] = DAMP * nsArr[srcIdx[e]];
      }
    #pragma unroll
    for (int fj=0; fj<4; ++fj){
      int c = n0 + wn + fj*16 + l15;
      float rt = rowterm[c], ct = constterm[c];
      #pragma unroll
      for (int fi=0; fi<4; ++fi){
        #pragma unroll
        for (int r=0;r<4;++r){
          size_t rowg = (size_t)(m0 + wm + fi*16 + grp*4 + r);
          ((float*)Cptr)[rowg*Nout + c] = acc[fi][fj][r] + cvals[fi][r]*rt + ct;
        }
      }
    }
  } else { // EPI == 5
    int prow[4][4];
    #pragma unroll
    for (int fi=0; fi<4; ++fi)
      #pragma unroll
      for (int r=0;r<4;++r)
        prow[fi][r] = posArr[m0 + wm + fi*16 + grp*4 + r];
    #pragma unroll
    for (int fj=0; fj<4; ++fj){
      int c = n0 + wn + fj*16 + l15;
      float bv = bias[c];
      #pragma unroll
      for (int fi=0; fi<4; ++fi){
        #pragma unroll
        for (int r=0;r<4;++r)
          ((u16*)Cptr)[(size_t)prow[fi][r]*Nout + c] = f2b(acc[fi][fj][r] + bv);
      }
    }
  }
}

// ---------------- segment sum over CSR-sorted w (contiguous streaming) ----------------
__global__ __launch_bounds__(256)
void k_segsum4(const ushort2* __restrict__ w2, const float2* __restrict__ o2,
               const int* __restrict__ ofs,
               float* __restrict__ nsA, float* __restrict__ invn, u16* __restrict__ ob,
               float* __restrict__ cross, float* __restrict__ colsum0, float* __restrict__ colsumsq,
               float* __restrict__ sumc, float* __restrict__ sumc2)
{
  int i0 = blockIdx.x*4, t = threadIdx.x;
  int wid = t>>6, lane = t&63;
  __shared__ float r1[4], r2[4];
  float cs0=0.f, cs1=0.f, sq0=0.f, sq1=0.f, cr0=0.f, cr1=0.f;
  #pragma unroll 1
  for (int u=0; u<4; ++u){
    int i = i0+u;
    int st = ofs[i], en = ofs[i+1];
    float a0=0.f, a1=0.f;
    for (int p=st; p<en; ++p){
      ushort2 v = w2[(size_t)p*256 + t];
      float f0=b2f(v.x), f1=b2f(v.y);
      a0+=f0; a1+=f1; sq0+=f0*f0; sq1+=f1*f1;
    }
    float2 o = o2[(size_t)i*256 + t];
    float o0 = o.x + DAMP*a0, o1 = o.y + DAMP*a1;
    float nsp = o0+o1, qp = o0*o0+o1*o1;
    for (int m=32;m>0;m>>=1){ nsp += __shfl_xor(nsp,m); qp += __shfl_xor(qp,m); }
    if (lane==0){ r1[wid]=nsp; r2[wid]=qp; }
    __syncthreads();
    float nsv = r1[0]+r1[1]+r1[2]+r1[3];
    float q   = r2[0]+r2[1]+r2[2]+r2[3];
    __syncthreads();
    if (t==0){
      nsA[i]=nsv; invn[i]=rsqrtf(q);
      float degf=(float)(en-st);
      atomicAdd(sumc,  DAMP*degf*nsv);
      atomicAdd(sumc2, DAMP*DAMP*degf*nsv*nsv);
    }
    ushort2 uo; uo.x=f2b(o0); uo.y=f2b(o1);
    ((ushort2*)ob)[(size_t)i*256+t]=uo;
    cs0+=a0; cs1+=a1; cr0+=DAMP*nsv*a0; cr1+=DAMP*nsv*a1;
  }
  atomicAdd(&colsum0[2*t],  cs0); atomicAdd(&colsum0[2*t+1],  cs1);
  atomicAdd(&colsumsq[2*t], sq0); atomicAdd(&colsumsq[2*t+1], sq1);
  atomicAdd(&cross[2*t],    cr0); atomicAdd(&cross[2*t+1],    cr1);
}

// out_bf16 [8192][512] -> outT [512][8192]
__global__ __launch_bounds__(256)
void k_transpose(const u16* __restrict__ in, u16* __restrict__ out){
  __shared__ u16 tile[64][65];
  int r0 = blockIdx.x*64, c0 = blockIdx.y*64;
  int t = threadIdx.x;
  int rr = t>>2, cc = (t&3)*16;
  const u16* ip = in + (size_t)(r0+rr)*512 + c0 + cc;
  #pragma unroll
  for (int j=0;j<16;++j) tile[rr][cc+j] = ip[j];
  __syncthreads();
  int cr = t>>2, rb = (t&3)*16;
  u16* op = out + (size_t)(c0+cr)*8192 + r0 + rb;
  #pragma unroll
  for (int j=0;j<16;++j) op[j] = tile[rb+j][cr];
}

__global__ __launch_bounds__(512)
void k_bnfinal(const float* __restrict__ colsum0, const float* __restrict__ colsumsq,
               const float* __restrict__ cross, const float* __restrict__ sumc,
               const float* __restrict__ sumc2, const float* __restrict__ gamma,
               const float* __restrict__ beta, float* __restrict__ alphaA, float* __restrict__ bbA)
{
  int j = threadIdx.x;
  const float invE = 1.0f / (float)EE;
  float mean = (colsum0[j] + sumc[0]) * invE;
  float ex2  = (colsumsq[j] + 2.f*cross[j] + sumc2[0]) * invE;
  float var  = ex2 - mean*mean;
  float is   = rsqrtf(var + 1e-5f);
  float a    = gamma[j]*is;
  alphaA[j]  = a;
  bbA[j]     = beta[j] - mean*a;
}

__global__ __launch_bounds__(512)
void k_wprime(const float* __restrict__ Ww1, const float* __restrict__ alphaA,
              const float* __restrict__ bbA, const float* __restrict__ bw1,
              const float* __restrict__ bw0,
              float* __restrict__ Ww1p, float* __restrict__ rowterm, float* __restrict__ constt)
{
  __shared__ float red[512];
  int k = blockIdx.x, j = threadIdx.x;
  float wv = Ww1[(size_t)k*512 + j];
  float a  = alphaA[j];
  Ww1p[(size_t)k*512 + j] = wv*a;
  red[j] = wv*a; __syncthreads();
  for (int off=256; off>0; off>>=1){ if (j<off) red[j] += red[j+off]; __syncthreads(); }
  if (j == 0) rowterm[k] = red[0];
  __syncthreads();
  red[j] = wv*(bbA[j] + a*bw0[j]); __syncthreads();
  for (int off=256; off>0; off>>=1){ if (j<off) red[j] += red[j+off]; __syncthreads(); }
  if (j == 0) constt[k] = red[0] + bw1[k];
}

// Wc[k][m] = sum_j Ww1p[k][j] * Ww0[j][m]   (256x512 @ 512x256)
__global__ __launch_bounds__(256)
void k_wc(const float* __restrict__ Ww1p, const float* __restrict__ Ww0, float* __restrict__ Wc){
  int k = blockIdx.x, m = threadIdx.x;
  float s = 0.f;
  #pragma unroll 8
  for (int j=0;j<512;++j) s += Ww1p[(size_t)k*512+j] * Ww0[(size_t)j*256+m];
  Wc[(size_t)k*256+m] = s;
}

// ---------------- launch ----------------
extern "C" void kernel_launch(void* const* d_in, const int* in_sizes, int n_in,
                              void* d_out, int out_size, void* d_ws, size_t ws_size,
                              hipStream_t stream)
{
  const float* x    = (const float*)d_in[0];
  const float* ew   = (const float*)d_in[1];
  const int*   ei   = (const int*)  d_in[2];
  const float* W0   = (const float*)d_in[3];
  const float* b0   = (const float*)d_in[4];
  const float* Ww0  = (const float*)d_in[5];
  const float* bw0  = (const float*)d_in[6];
  const float* W1   = (const float*)d_in[7];
  const float* b1   = (const float*)d_in[8];
  const float* Ww1  = (const float*)d_in[9];
  const float* bw1  = (const float*)d_in[10];
  const float* gamma= (const float*)d_in[11];
  const float* beta = (const float*)d_in[12];
  const int* src = ei; // edge_index[0]

  char* ws = (char*)d_ws;
  u16*   w0    = (u16*)  (ws + 0ULL);            // [E][512] bf16, CSR-permuted rows
  float* out0  = (float*)(ws + 268435456ULL);    // [N][512] f32
  u16*   ob    = (u16*)  (ws + 285212672ULL);    // out bf16
  u16*   obT   = (u16*)  (ws + 293601280ULL);    // out^T bf16
  u16*   onew  = (u16*)  (ws + 301989888ULL);    // mixed out bf16 (written late)
  float* nsA   = (float*)(ws + 310378496ULL);    // [N]
  float* invn  = (float*)(ws + 310411264ULL);    // [N]
  int*   deg   = (int*)  (ws + 310444032ULL);    // [N]
  int*   ofs   = (int*)  (ws + 310476800ULL);    // [N+1]
  int*   cur   = (int*)  (ws + 310509824ULL);    // [N]
  float* stats = (float*)(ws + 311591168ULL);    // 4096 floats zeroed
  float* cross    = stats;
  float* colsum0  = stats + 512;
  float* colsumsq = stats + 1024;
  float* sumc     = stats + 1536;
  float* sumc2    = stats + 1537;
  float* lsum  = (float*)(ws + 311607552ULL);    // [N] f32 rowsums (zeroed)
  float* Ww1p   = (float*)(ws + 311640320ULL);   // [256][512] f32
  float* rowterm= (float*)(ws + 312164608ULL);   // [256]
  float* constt = (float*)(ws + 312165632ULL);   // [256]
  float* alphaA = (float*)(ws + 312166656ULL);   // [512]
  float* bbA    = (float*)(ws + 312168704ULL);   // [512]
  // lifetime-overlapped scratch (no new ws space):
  int*   pos   = (int*)onew;      // [E] int; dead before onew is written (attn pass 2)
  float* Wc    = (float*)out0;    // [256][256] f32; out0 dead after k_segsum4

  float* out1 = (float*)d_out;                 // [N][256]
  float* out2 = out1 + (size_t)NN*VDIM;        // [E][256]
  u16*   Pbuf = (u16*)out2;                    // P [8192][8192] bf16 scratch inside out2

  hipMemsetAsync(deg, 0, NN*sizeof(int), stream);
  hipMemsetAsync(stats, 0, 16384, stream);
  hipMemsetAsync(lsum, 0, NN*sizeof(float), stream);

  k_hist   <<<EE/256, 256, 0, stream>>>(src, deg);
  k_scan   <<<1, 1024, 0, stream>>>(deg, ofs, cur);
  k_permute<<<EE/256, 256, 0, stream>>>(src, cur, pos);

  // w = edge_weight @ Ww0^T + bw0 -> bf16, rows scatter-written to CSR order
  k_gemmw<5><<<dim3(2,2048), 512, 0, stream>>>(ew, Ww0, HDIM, EDIM, bw0, w0,
                                               nullptr, nullptr, nullptr, nullptr, pos);
  // out0 = x @ W0^T + b0 -> f32
  k_gemm<0,0,0><<<dim3(4,64), 256, 0, stream>>>(x, W0, NN, HDIM, VDIM, b0, out0, nullptr, nullptr);

  // segment sums (contiguous CSR ranges) + node scalars + norms + all BN stats
  k_segsum4<<<NN/4, 256, 0, stream>>>((const ushort2*)w0, (const float2*)out0, ofs,
                                      nsA, invn, ob, cross, colsum0, colsumsq, sumc, sumc2);
  k_transpose<<<dim3(128,8), 256, 0, stream>>>(ob, obT);
  k_bnfinal<<<1, 512, 0, stream>>>(colsum0, colsumsq, cross, sumc, sumc2, gamma, beta, alphaA, bbA);
  k_wprime<<<256, 512, 0, stream>>>(Ww1, alphaA, bbA, bw1, bw0, Ww1p, rowterm, constt);
  k_wc<<<256, 256, 0, stream>>>(Ww1p, Ww0, Wc);

  // attention pass 1: P = exp(cos-sim - eye), row sums -> lsum
  k_gemm<1,1,3><<<dim3(64,64), 256, 0, stream>>>(ob, ob, NN, NN, HDIM, nullptr, Pbuf, invn, lsum);
  // attention pass 2: onew = (P @ V) / lsum
  k_gemm<1,1,4><<<dim3(4,64), 256, 0, stream>>>(Pbuf, obT, NN, HDIM, NN, nullptr, onew, nullptr, lsum);

  // out2 = ew @ Wc^T + c_e*rowterm + constt (single fetch of ew: full N per block)
  k_gemmw<2><<<dim3(1,2048), 512, 0, stream>>>(ew, Wc, VDIM, EDIM, nullptr, out2,
                                               src, nsA, rowterm, constt, nullptr);
  // out1 = mixed_out @ W1^T + b1
  k_gemm<1,0,0><<<dim3(2,64), 256, 0, stream>>>(onew, W1, NN, VDIM, HDIM, b1, out1, nullptr, nullptr);
}

// Round 5
// 1080.966 us; speedup vs baseline: 2.0367x; 1.0164x over previous
//
#include <hip/hip_runtime.h>

typedef unsigned short u16;
typedef __attribute__((ext_vector_type(8))) short bh8;   // 8 x bf16 (raw bits)
typedef __attribute__((ext_vector_type(4))) float f4v;   // MFMA C frag

#define NN 8192
#define EE 262144
#define VDIM 256
#define EDIM 256
#define HDIM 512
#define DAMP 0.45f

__device__ __forceinline__ float b2f(u16 u){ unsigned int x = ((unsigned int)u)<<16; return __builtin_bit_cast(float, x); }
__device__ __forceinline__ u16 f2b(float f){ unsigned int x = __builtin_bit_cast(unsigned int, f); x = (x + 0x7fffu + ((x>>16)&1u)) >> 16; return (u16)x; }

__device__ __forceinline__ void gload16(const void* g, void* l){
  __builtin_amdgcn_global_load_lds((const __attribute__((address_space(1))) void*)g,
                                   (__attribute__((address_space(3))) void*)l, 16, 0, 0);
}

// ---------------- CSR build ----------------
__global__ __launch_bounds__(256) void k_hist(const int* __restrict__ src, int* __restrict__ deg){
  int e = blockIdx.x*256 + threadIdx.x;
  if (e < EE) atomicAdd(&deg[src[e]], 1);
}

__global__ __launch_bounds__(1024) void k_scan(const int* __restrict__ deg, int* __restrict__ ofs, int* __restrict__ cur){
  __shared__ int lds[1024];
  int t = threadIdx.x;
  int v[8], pre[8]; int s = 0;
  #pragma unroll
  for (int j=0;j<8;++j){ v[j] = deg[t*8+j]; }
  #pragma unroll
  for (int j=0;j<8;++j){ pre[j] = s; s += v[j]; }
  lds[t] = s; __syncthreads();
  int run = s;
  for (int off=1; off<1024; off<<=1){
    int x = (t>=off) ? lds[t-off] : 0;
    __syncthreads();
    lds[t] += x;
    __syncthreads();
  }
  int excl = lds[t] - run;
  #pragma unroll
  for (int j=0;j<8;++j){ int o = excl + pre[j]; ofs[t*8+j] = o; cur[t*8+j] = o; }
  if (t == 1023) ofs[NN] = excl + run;
}

// pos[e] = CSR slot of edge e; elist[slot] = e (inverse)
__global__ __launch_bounds__(256) void k_permute(const int* __restrict__ src, int* __restrict__ cur,
                                                 int* __restrict__ pos, int* __restrict__ elist){
  int e = blockIdx.x*256 + threadIdx.x;
  if (e < EE){ int p = atomicAdd(&cur[src[e]], 1); pos[e] = p; elist[p] = e; }
}

// f32 -> bf16 bulk convert (8 elems/thread)
__global__ __launch_bounds__(256) void k_cvtW(const float* __restrict__ in, u16* __restrict__ out, int n8){
  int i = blockIdx.x*256 + threadIdx.x;
  if (i < n8){
    const f4v* p = (const f4v*)(in + (size_t)i*8);
    f4v f0 = p[0], f1 = p[1];
    bh8 v;
    #pragma unroll
    for (int j=0;j<4;++j){ v[j]=(short)f2b(f0[j]); v[j+4]=(short)f2b(f1[j]); }
    ((bh8*)out)[i] = v;
  }
}

// ---------------- narrow GEMM (128x128 tile, 256 thr): C = A @ B^T ----------------
// EPI 0: f32 out + bias
// EPI 3: P = exp(scale) bf16 out + row-sum atomics (attention pass 1)
// EPI 4: bf16 out, scaled by 1/lsum[row]          (attention pass 2)
template<int A_BF16, int B_BF16, int EPI>
__global__ __launch_bounds__(256)
void k_gemm(const void* __restrict__ Aptr, const void* __restrict__ Bptr,
            int M, int N, int K, const float* __restrict__ bias,
            void* __restrict__ Cptr,
            const float* __restrict__ invnA, float* __restrict__ lsum)
{
  __shared__ u16 As[128*32];
  __shared__ u16 Bs[128*32];
  const int t = threadIdx.x;
  const int m0 = blockIdx.y*128, n0 = blockIdx.x*128;
  const int wid = t>>6, lane = t&63, l15 = lane&15, grp = lane>>4;
  const int wm = (wid>>1)*64, wn = (wid&1)*64;
  const int srow = t>>1, shalf = t&1;
  const int rlane = lane>>2, clane = lane&3;

  f4v acc[4][4];
  #pragma unroll
  for (int i=0;i<4;++i)
    #pragma unroll
    for (int j=0;j<4;++j) acc[i][j] = (f4v)0.0f;

  for (int kt=0; kt<K; kt+=32){
    __syncthreads();
    if (A_BF16){ // async direct global->LDS, 16B/lane
      const u16* g0 = (const u16*)Aptr + (size_t)(m0 + wid*32 + rlane)*K + kt + clane*8;
      gload16(g0,                 &As[wid*1024]);
      gload16(g0 + (size_t)16*K,  &As[wid*1024 + 512]);
    } else {
      u16* dst = &As[srow*32 + shalf*16];
      const float* ap = (const float*)Aptr + (size_t)(m0+srow)*K + kt + shalf*16;
      const f4v* ap4 = (const f4v*)ap;
      f4v f0 = ap4[0], f1 = ap4[1], f2 = ap4[2], f3 = ap4[3];
      bh8 v0, v1;
      #pragma unroll
      for (int j=0;j<4;++j){ v0[j]=(short)f2b(f0[j]); v0[j+4]=(short)f2b(f1[j]); v1[j]=(short)f2b(f2[j]); v1[j+4]=(short)f2b(f3[j]); }
      ((bh8*)dst)[0] = v0; ((bh8*)dst)[1] = v1;
    }
    if (B_BF16){
      const u16* g0 = (const u16*)Bptr + (size_t)(n0 + wid*32 + rlane)*K + kt + clane*8;
      gload16(g0,                 &Bs[wid*1024]);
      gload16(g0 + (size_t)16*K,  &Bs[wid*1024 + 512]);
    } else {
      u16* dst = &Bs[srow*32 + shalf*16];
      const float* bp = (const float*)Bptr + (size_t)(n0+srow)*K + kt + shalf*16;
      const f4v* bp4 = (const f4v*)bp;
      f4v f0 = bp4[0], f1 = bp4[1], f2 = bp4[2], f3 = bp4[3];
      bh8 v0, v1;
      #pragma unroll
      for (int j=0;j<4;++j){ v0[j]=(short)f2b(f0[j]); v0[j+4]=(short)f2b(f1[j]); v1[j]=(short)f2b(f2[j]); v1[j+4]=(short)f2b(f3[j]); }
      ((bh8*)dst)[0] = v0; ((bh8*)dst)[1] = v1;
    }
    __syncthreads();
    bh8 af[4], bfv[4];
    #pragma unroll
    for (int f=0; f<4; ++f) af[f]  = *(const bh8*)&As[(wm + f*16 + l15)*32 + grp*8];
    #pragma unroll
    for (int f=0; f<4; ++f) bfv[f] = *(const bh8*)&Bs[(wn + f*16 + l15)*32 + grp*8];
    #pragma unroll
    for (int fi=0; fi<4; ++fi)
      #pragma unroll
      for (int fj=0; fj<4; ++fj)
        acc[fi][fj] = __builtin_amdgcn_mfma_f32_16x16x32_bf16(af[fi], bfv[fj], acc[fi][fj], 0, 0, 0);
  }

  if (EPI == 3){ // attention pass 1
    float ic[4];
    #pragma unroll
    for (int fj=0; fj<4; ++fj) ic[fj] = invnA[n0 + wn + fj*16 + l15];
    #pragma unroll
    for (int fi=0; fi<4; ++fi){
      #pragma unroll
      for (int r=0;r<4;++r){
        int rowg = m0 + wm + fi*16 + grp*4 + r;
        float iq = invnA[rowg];
        float rs = 0.f;
        #pragma unroll
        for (int fj=0; fj<4; ++fj){
          int c = n0 + wn + fj*16 + l15;
          float s = acc[fi][fj][r]*iq*ic[fj];
          float p = (rowg == c) ? 1.0f : __expf(s);
          ((u16*)Cptr)[(size_t)rowg*N + c] = f2b(p);
          rs += p;
        }
        rs += __shfl_xor(rs,1); rs += __shfl_xor(rs,2); rs += __shfl_xor(rs,4); rs += __shfl_xor(rs,8);
        if (l15 == 0) atomicAdd(&lsum[rowg], rs);
      }
    }
    return;
  }

  float ilv[4][4];
  if (EPI == 4){
    #pragma unroll
    for (int fi=0; fi<4; ++fi)
      #pragma unroll
      for (int r=0;r<4;++r)
        ilv[fi][r] = 1.0f / lsum[m0 + wm + fi*16 + grp*4 + r];
  }
  #pragma unroll
  for (int fj=0; fj<4; ++fj){
    int c = n0 + wn + fj*16 + l15;
    float bv = (EPI == 0 && bias) ? bias[c] : 0.f;
    #pragma unroll
    for (int fi=0; fi<4; ++fi){
      #pragma unroll
      for (int r=0;r<4;++r){
        size_t rowg = (size_t)(m0 + wm + fi*16 + grp*4 + r);
        float v = acc[fi][fj][r];
        if (EPI == 0)      ((float*)Cptr)[rowg*N + c] = v + bv;
        else               ((u16*)Cptr)[rowg*N + c]  = f2b(v * ilv[fi][r]);
      }
    }
  }
}

// ---------------- wide edge GEMM (128 x BN tile, 512 thr, 8 waves) ----------------
// A: [M,K] (f32 VALU-staged or bf16 via global_load_lds). B: [BN,K] bf16 via global_load_lds.
// Full N covered per block -> A fetched exactly once. XCD-swizzled 1-D grid (2048 % 8 == 0).
// EPI 5: bf16 out + bias, rows scattered through mapArr=pos   (w = ew@Ww0^T+bw0, CSR order)
// EPI 2: f32 out + c_e*rowterm + constterm, rows scattered through mapArr=elist (BN-folded)
template<int A_BF16, int BN, int EPI>
__global__ __launch_bounds__(512, 2)
void k_gemmw2(const void* __restrict__ Aptr, const u16* __restrict__ Bptr,
              int K, const float* __restrict__ bias, void* __restrict__ Cptr,
              const int* __restrict__ mapArr, const int* __restrict__ srcIdx,
              const float* __restrict__ nsArr, const float* __restrict__ rowterm,
              const float* __restrict__ constterm)
{
  constexpr int NF = BN/64;            // col frags per wave (4 col-waves): 512->8, 256->4
  __shared__ u16 As[128*32];
  __shared__ u16 Bs[BN*32];
  const int t = threadIdx.x;
  const int tile = ((int)blockIdx.x & 7)*((int)gridDim.x>>3) + ((int)blockIdx.x>>3);
  const int m0 = tile*128;
  const int wid = t>>6, lane = t&63, l15 = lane&15, grp = lane>>4;
  const int wm = (wid>>2)*64;          // 2 row-waves
  const int wn = (wid&3)*(BN/4);       // 4 col-waves

  f4v acc[4][NF];
  #pragma unroll
  for (int i=0;i<4;++i)
    #pragma unroll
    for (int j=0;j<NF;++j) acc[i][j] = (f4v)0.0f;

  for (int kt=0; kt<K; kt+=32){
    __syncthreads();
    if (A_BF16){ // 1 gload16/thread covers [128][32] bf16
      const u16* g0 = (const u16*)Aptr + (size_t)(m0 + wid*16 + (lane>>2))*K + kt + (lane&3)*8;
      gload16(g0, &As[wid*512]);
    } else {     // f32 -> bf16 VALU stage, 8 floats/thread
      const float* ap = (const float*)Aptr + (size_t)(m0 + (t>>2))*K + kt + (t&3)*8;
      const f4v* ap4 = (const f4v*)ap;
      f4v f0 = ap4[0], f1 = ap4[1];
      bh8 v;
      #pragma unroll
      for (int j=0;j<4;++j){ v[j]=(short)f2b(f0[j]); v[j+4]=(short)f2b(f1[j]); }
      *(bh8*)&As[(t>>2)*32 + (t&3)*8] = v;
    }
    #pragma unroll
    for (int j=0;j<BN/128;++j){ // B: bf16, BN/128 gload16/thread
      const u16* g0 = Bptr + (size_t)(j*128 + wid*16 + (lane>>2))*K + kt + (lane&3)*8;
      gload16(g0, &Bs[wid*512 + j*4096]);
    }
    __syncthreads();
    bh8 af[4], bfv[NF];
    #pragma unroll
    for (int f=0; f<4; ++f)  af[f]  = *(const bh8*)&As[(wm + f*16 + l15)*32 + grp*8];
    #pragma unroll
    for (int f=0; f<NF; ++f) bfv[f] = *(const bh8*)&Bs[(wn + f*16 + l15)*32 + grp*8];
    #pragma unroll
    for (int fi=0; fi<4; ++fi)
      #pragma unroll
      for (int fj=0; fj<NF; ++fj)
        acc[fi][fj] = __builtin_amdgcn_mfma_f32_16x16x32_bf16(af[fi], bfv[fj], acc[fi][fj], 0, 0, 0);
  }

  int prow[4][4];
  float cvals[4][4];
  #pragma unroll
  for (int fi=0; fi<4; ++fi)
    #pragma unroll
    for (int r=0;r<4;++r){
      int slot = m0 + wm + fi*16 + grp*4 + r;
      int mp = mapArr[slot];
      prow[fi][r] = mp;
      if (EPI == 2) cvals[fi][r] = DAMP * nsArr[srcIdx[mp]];
    }
  #pragma unroll
  for (int fj=0; fj<NF; ++fj){
    int c = wn + fj*16 + l15;
    float bv = 0.f, rt = 0.f, ct = 0.f;
    if (EPI == 2){ rt = rowterm[c]; ct = constterm[c]; }
    else bv = bias[c];
    #pragma unroll
    for (int fi=0; fi<4; ++fi){
      #pragma unroll
      for (int r=0;r<4;++r){
        size_t rowg = (size_t)prow[fi][r];
        if (EPI == 5) ((u16*)Cptr)[rowg*BN + c]  = f2b(acc[fi][fj][r] + bv);
        else          ((float*)Cptr)[rowg*BN + c] = acc[fi][fj][r] + cvals[fi][r]*rt + ct;
      }
    }
  }
}

// ---------------- segment sum over CSR-sorted w (contiguous streaming) ----------------
__global__ __launch_bounds__(256)
void k_segsum4(const ushort2* __restrict__ w2, const float2* __restrict__ o2,
               const int* __restrict__ ofs,
               float* __restrict__ nsA, float* __restrict__ invn, u16* __restrict__ ob,
               float* __restrict__ cross, float* __restrict__ colsum0, float* __restrict__ colsumsq,
               float* __restrict__ sumc, float* __restrict__ sumc2)
{
  int i0 = blockIdx.x*4, t = threadIdx.x;
  int wid = t>>6, lane = t&63;
  __shared__ float r1[4], r2[4];
  float cs0=0.f, cs1=0.f, sq0=0.f, sq1=0.f, cr0=0.f, cr1=0.f;
  #pragma unroll 1
  for (int u=0; u<4; ++u){
    int i = i0+u;
    int st = ofs[i], en = ofs[i+1];
    float a0=0.f, a1=0.f;
    for (int p=st; p<en; ++p){
      ushort2 v = w2[(size_t)p*256 + t];
      float f0=b2f(v.x), f1=b2f(v.y);
      a0+=f0; a1+=f1; sq0+=f0*f0; sq1+=f1*f1;
    }
    float2 o = o2[(size_t)i*256 + t];
    float o0 = o.x + DAMP*a0, o1 = o.y + DAMP*a1;
    float nsp = o0+o1, qp = o0*o0+o1*o1;
    for (int m=32;m>0;m>>=1){ nsp += __shfl_xor(nsp,m); qp += __shfl_xor(qp,m); }
    if (lane==0){ r1[wid]=nsp; r2[wid]=qp; }
    __syncthreads();
    float nsv = r1[0]+r1[1]+r1[2]+r1[3];
    float q   = r2[0]+r2[1]+r2[2]+r2[3];
    __syncthreads();
    if (t==0){
      nsA[i]=nsv; invn[i]=rsqrtf(q);
      float degf=(float)(en-st);
      atomicAdd(sumc,  DAMP*degf*nsv);
      atomicAdd(sumc2, DAMP*DAMP*degf*nsv*nsv);
    }
    ushort2 uo; uo.x=f2b(o0); uo.y=f2b(o1);
    ((ushort2*)ob)[(size_t)i*256+t]=uo;
    cs0+=a0; cs1+=a1; cr0+=DAMP*nsv*a0; cr1+=DAMP*nsv*a1;
  }
  atomicAdd(&colsum0[2*t],  cs0); atomicAdd(&colsum0[2*t+1],  cs1);
  atomicAdd(&colsumsq[2*t], sq0); atomicAdd(&colsumsq[2*t+1], sq1);
  atomicAdd(&cross[2*t],    cr0); atomicAdd(&cross[2*t+1],    cr1);
}

// out_bf16 [8192][512] -> outT [512][8192]
__global__ __launch_bounds__(256)
void k_transpose(const u16* __restrict__ in, u16* __restrict__ out){
  __shared__ u16 tile[64][65];
  int r0 = blockIdx.x*64, c0 = blockIdx.y*64;
  int t = threadIdx.x;
  int rr = t>>2, cc = (t&3)*16;
  const u16* ip = in + (size_t)(r0+rr)*512 + c0 + cc;
  #pragma unroll
  for (int j=0;j<16;++j) tile[rr][cc+j] = ip[j];
  __syncthreads();
  int cr = t>>2, rb = (t&3)*16;
  u16* op = out + (size_t)(c0+cr)*8192 + r0 + rb;
  #pragma unroll
  for (int j=0;j<16;++j) op[j] = tile[rb+j][cr];
}

__global__ __launch_bounds__(512)
void k_bnfinal(const float* __restrict__ colsum0, const float* __restrict__ colsumsq,
               const float* __restrict__ cross, const float* __restrict__ sumc,
               const float* __restrict__ sumc2, const float* __restrict__ gamma,
               const float* __restrict__ beta, float* __restrict__ alphaA, float* __restrict__ bbA)
{
  int j = threadIdx.x;
  const float invE = 1.0f / (float)EE;
  float mean = (colsum0[j] + sumc[0]) * invE;
  float ex2  = (colsumsq[j] + 2.f*cross[j] + sumc2[0]) * invE;
  float var  = ex2 - mean*mean;
  float is   = rsqrtf(var + 1e-5f);
  float a    = gamma[j]*is;
  alphaA[j]  = a;
  bbA[j]     = beta[j] - mean*a;
}

// Ww1pb[k][j] = bf16(alpha_j * Ww1[k][j]); rowterm[k]=sum_j alpha_j Ww1[k][j];
// constt[k] = sum_j bbA_j Ww1[k][j] + bw1[k]
__global__ __launch_bounds__(512)
void k_wprime(const float* __restrict__ Ww1, const float* __restrict__ alphaA,
              const float* __restrict__ bbA, const float* __restrict__ bw1,
              u16* __restrict__ Ww1pb, float* __restrict__ rowterm, float* __restrict__ constt)
{
  __shared__ float red[512];
  int k = blockIdx.x, j = threadIdx.x;
  float wv = Ww1[(size_t)k*512 + j];
  float a  = alphaA[j];
  Ww1pb[(size_t)k*512 + j] = f2b(wv*a);
  red[j] = wv*a; __syncthreads();
  for (int off=256; off>0; off>>=1){ if (j<off) red[j] += red[j+off]; __syncthreads(); }
  if (j == 0) rowterm[k] = red[0];
  __syncthreads();
  red[j] = wv*bbA[j]; __syncthreads();
  for (int off=256; off>0; off>>=1){ if (j<off) red[j] += red[j+off]; __syncthreads(); }
  if (j == 0) constt[k] = red[0] + bw1[k];
}

// ---------------- launch ----------------
extern "C" void kernel_launch(void* const* d_in, const int* in_sizes, int n_in,
                              void* d_out, int out_size, void* d_ws, size_t ws_size,
                              hipStream_t stream)
{
  const float* x    = (const float*)d_in[0];
  const float* ew   = (const float*)d_in[1];
  const int*   ei   = (const int*)  d_in[2];
  const float* W0   = (const float*)d_in[3];
  const float* b0   = (const float*)d_in[4];
  const float* Ww0  = (const float*)d_in[5];
  const float* bw0  = (const float*)d_in[6];
  const float* W1   = (const float*)d_in[7];
  const float* b1   = (const float*)d_in[8];
  const float* Ww1  = (const float*)d_in[9];
  const float* bw1  = (const float*)d_in[10];
  const float* gamma= (const float*)d_in[11];
  const float* beta = (const float*)d_in[12];
  const int* src = ei; // edge_index[0]

  char* ws = (char*)d_ws;
  u16*   w0    = (u16*)  (ws + 0ULL);            // [E][512] bf16, CSR-permuted rows
  float* out0  = (float*)(ws + 268435456ULL);    // [N][512] f32
  u16*   ob    = (u16*)  (ws + 285212672ULL);    // out bf16
  u16*   obT   = (u16*)  (ws + 293601280ULL);    // out^T bf16
  u16*   onew  = (u16*)  (ws + 301989888ULL);    // mixed out bf16 (written late)
  float* nsA   = (float*)(ws + 310378496ULL);    // [N]
  float* invn  = (float*)(ws + 310411264ULL);    // [N]
  int*   deg   = (int*)  (ws + 310444032ULL);    // [N]
  int*   ofs   = (int*)  (ws + 310476800ULL);    // [N+1]
  int*   cur   = (int*)  (ws + 310509824ULL);    // [N]
  int*   elist = (int*)  (ws + 310542592ULL);    // [E] int (1 MB)
  float* stats = (float*)(ws + 311591168ULL);    // 4096 floats zeroed
  float* cross    = stats;
  float* colsum0  = stats + 512;
  float* colsumsq = stats + 1024;
  float* sumc     = stats + 1536;
  float* sumc2    = stats + 1537;
  float* lsum   = (float*)(ws + 311607552ULL);   // [N] f32 rowsums (zeroed)
  u16*   Ww1pb  = (u16*)  (ws + 311640320ULL);   // [256][512] bf16
  float* rowterm= (float*)(ws + 312164608ULL);   // [256]
  float* constt = (float*)(ws + 312165632ULL);   // [256]
  float* alphaA = (float*)(ws + 312166656ULL);   // [512]
  float* bbA    = (float*)(ws + 312168704ULL);   // [512]
  u16*   Ww0b   = (u16*)  (ws + 312170752ULL);   // [512][256] bf16 (256 KB)
  // lifetime-overlapped scratch:
  int*   pos   = (int*)onew;      // [E] int; dead before onew is written (attn pass 2)

  float* out1 = (float*)d_out;                 // [N][256]
  float* out2 = out1 + (size_t)NN*VDIM;        // [E][256]
  u16*   Pbuf = (u16*)out2;                    // P [8192][8192] bf16 scratch inside out2

  hipMemsetAsync(deg, 0, NN*sizeof(int), stream);
  hipMemsetAsync(stats, 0, 16384, stream);
  hipMemsetAsync(lsum, 0, NN*sizeof(float), stream);

  k_hist   <<<EE/256, 256, 0, stream>>>(src, deg);
  k_scan   <<<1, 1024, 0, stream>>>(deg, ofs, cur);
  k_permute<<<EE/256, 256, 0, stream>>>(src, cur, pos, elist);
  k_cvtW   <<<64, 256, 0, stream>>>(Ww0, Ww0b, HDIM*EDIM/8);

  // w = ew @ Ww0^T + bw0 -> bf16, rows scatter-written to CSR order (single ew fetch)
  k_gemmw2<0,512,5><<<2048, 512, 0, stream>>>(ew, Ww0b, EDIM, bw0, w0,
                                              pos, nullptr, nullptr, nullptr, nullptr);
  // out0 = x @ W0^T + b0 -> f32
  k_gemm<0,0,0><<<dim3(4,64), 256, 0, stream>>>(x, W0, NN, HDIM, VDIM, b0, out0, nullptr, nullptr);

  // segment sums (contiguous CSR ranges) + node scalars + norms + all BN stats
  k_segsum4<<<NN/4, 256, 0, stream>>>((const ushort2*)w0, (const float2*)out0, ofs,
                                      nsA, invn, ob, cross, colsum0, colsumsq, sumc, sumc2);
  k_transpose<<<dim3(128,8), 256, 0, stream>>>(ob, obT);
  k_bnfinal<<<1, 512, 0, stream>>>(colsum0, colsumsq, cross, sumc, sumc2, gamma, beta, alphaA, bbA);
  k_wprime<<<256, 512, 0, stream>>>(Ww1, alphaA, bbA, bw1, Ww1pb, rowterm, constt);

  // attention pass 1: P = exp(cos-sim - eye), row sums -> lsum
  k_gemm<1,1,3><<<dim3(64,64), 256, 0, stream>>>(ob, ob, NN, NN, HDIM, nullptr, Pbuf, invn, lsum);
  // attention pass 2: onew = (P @ V) / lsum   (overwrites pos region)
  k_gemm<1,1,4><<<dim3(4,64), 256, 0, stream>>>(Pbuf, obT, NN, HDIM, NN, nullptr, onew, nullptr, lsum);

  // out2 = w0 @ (alpha*Ww1)^T + c_e*rowterm + constt, rows scattered via elist
  k_gemmw2<1,256,2><<<2048, 512, 0, stream>>>(w0, Ww1pb, HDIM, nullptr, out2,
                                              elist, src, nsA, rowterm, constt);
  // out1 = mixed_out @ W1^T + b1
  k_gemm<1,0,0><<<dim3(2,64), 256, 0, stream>>>(onew, W1, NN, VDIM, HDIM, b1, out1, nullptr, nullptr);
}